// Round 9
// baseline (949.875 us; speedup 1.0000x reference)
//
#include <hip/hip_runtime.h>
#include <hip/hip_bf16.h>
#include <cstdint>
#include <cstddef>

#define DI __device__ __forceinline__

DI float lrelu(float x) { return x > 0.f ? x : 0.2f * x; }
DI int clampi(int v, int lo, int hi) { return v < lo ? lo : (v > hi ? hi : v); }
DI float clampf(float v) { return fminf(fmaxf(v, -1e15f), 1e15f); }

// dual-mode load of a "float tensor": mode 0 = bf16 storage, mode 1 = fp32 storage
DI float ldm(const void* p, int i, int mode) {
    if (mode) return ((const float*)p)[i];
    return __bfloat162float(((const __hip_bfloat16*)p)[i]);
}

// better-than comparator: smaller value wins; tie -> smaller index (matches top_k)
DI void ins3(float v, int ix, float bv[3], int bi[3]) {
    bool b2 = (v < bv[2]) || (v == bv[2] && ix < bi[2]);
    if (!b2) return;
    bool b0 = (v < bv[0]) || (v == bv[0] && ix < bi[0]);
    bool b1 = (v < bv[1]) || (v == bv[1] && ix < bi[1]);
    if (b0) {
        bv[2] = bv[1]; bi[2] = bi[1];
        bv[1] = bv[0]; bi[1] = bi[0];
        bv[0] = v;     bi[0] = ix;
    } else if (b1) {
        bv[2] = bv[1]; bi[2] = bi[1];
        bv[1] = v;     bi[1] = ix;
    } else {
        bv[2] = v;     bi[2] = ix;
    }
}

// ---------------- dtype detection ----------------
__global__ void k_detect(const unsigned short* __restrict__ u, int n, int* __restrict__ flag) {
    int i = blockIdx.x * 256 + threadIdx.x;
    if (i < n) {
        if (((u[i] >> 7) & 0xFF) == 0xFF) atomicOr(flag, 1);
    }
}

// ---------------- edge sort (counting sort by dst) ----------------
__global__ void k_hist(const int* __restrict__ dst, int E, int* __restrict__ deg, int N) {
    int e = blockIdx.x * 256 + threadIdx.x;
    if (e < E) {
        unsigned d = (unsigned)dst[e];
        if (d < (unsigned)N) atomicAdd(&deg[d], 1);
    }
}

__global__ __launch_bounds__(1024) void k_scan(const int* __restrict__ deg, int* __restrict__ off, int N) {
    __shared__ int s[1024];
    __shared__ int carry_s;
    int tid = threadIdx.x;
    if (tid == 0) carry_s = 0;
    __syncthreads();
    for (int base = 0; base < N; base += 1024) {
        int i = base + tid;
        int v = (i < N) ? deg[i] : 0;
        s[tid] = v;
        __syncthreads();
        for (int d = 1; d < 1024; d <<= 1) {
            int t = (tid >= d) ? s[tid - d] : 0;
            __syncthreads();
            s[tid] += t;
            __syncthreads();
        }
        if (i < N) off[i] = carry_s + s[tid] - v;
        int tot = s[1023];
        __syncthreads();
        if (tid == 0) carry_s += tot;
        __syncthreads();
    }
    if (tid == 0) off[N] = carry_s;
}

__global__ void k_scatter(const int* __restrict__ src, const int* __restrict__ dst, int E,
                          const int* __restrict__ off, int* __restrict__ cur, int* __restrict__ sorted,
                          int N) {
    int e = blockIdx.x * 256 + threadIdx.x;
    if (e < E) {
        unsigned d = (unsigned)dst[e];
        if (d < (unsigned)N) {
            int p = off[d] + atomicAdd(&cur[d], 1);
            sorted[p] = clampi(src[e], 0, N - 1);
        }
    }
}

// ---------------- GAT: linear + attention scores (external input, dual-mode) ----------------
template <int FIN>
__global__ __launch_bounds__(128) void k_lin(const void* __restrict__ x,
                                             const void* __restrict__ W,
                                             const void* __restrict__ av_src,
                                             const void* __restrict__ av_dst,
                                             const int* __restrict__ mode_p,
                                             float* __restrict__ h, float* __restrict__ as_,
                                             float* __restrict__ ad_, int N) {
    int mode = *mode_p;
    int n = blockIdx.x;
    int f = threadIdx.x;
    __shared__ float xs[FIN];
    if (f < FIN) xs[f] = ldm(x, n * FIN + f, mode);
    __syncthreads();
    float acc = 0.f;
#pragma unroll
    for (int k = 0; k < FIN; k++) acc += xs[k] * ldm(W, k * 128 + f, mode);
    acc = clampf(acc);
    h[(size_t)n * 128 + f] = acc;
    __shared__ float r1[128], r2[128];
    r1[f] = acc * ldm(av_src, f, mode);
    r2[f] = acc * ldm(av_dst, f, mode);
    __syncthreads();
    for (int s2 = 64; s2 > 0; s2 >>= 1) {
        if (f < s2) { r1[f] += r1[f + s2]; r2[f] += r2[f + s2]; }
        __syncthreads();
    }
    if (f == 0) { as_[n] = clampf(r1[0]); ad_[n] = clampf(r2[0]); }
}

// ---------------- GAT layer-2 linear: INTERNAL fp32 input, dual-mode weights ----------------
__global__ __launch_bounds__(128) void k_lin_f32(const float* __restrict__ x,
                                                 const void* __restrict__ W,
                                                 const void* __restrict__ av_src,
                                                 const void* __restrict__ av_dst,
                                                 const int* __restrict__ mode_p,
                                                 float* __restrict__ h, float* __restrict__ as_,
                                                 float* __restrict__ ad_, int N) {
    int mode = *mode_p;
    int n = blockIdx.x;
    int f = threadIdx.x;
    __shared__ float xs[128];
    xs[f] = x[(size_t)n * 128 + f];
    __syncthreads();
    float acc = 0.f;
#pragma unroll
    for (int k = 0; k < 128; k++) acc += xs[k] * ldm(W, k * 128 + f, mode);
    acc = clampf(acc);
    h[(size_t)n * 128 + f] = acc;
    __shared__ float r1[128], r2[128];
    r1[f] = acc * ldm(av_src, f, mode);
    r2[f] = acc * ldm(av_dst, f, mode);
    __syncthreads();
    for (int s2 = 64; s2 > 0; s2 >>= 1) {
        if (f < s2) { r1[f] += r1[f + s2]; r2[f] += r2[f + s2]; }
        __syncthreads();
    }
    if (f == 0) { as_[n] = clampf(r1[0]); ad_[n] = clampf(r2[0]); }
}

// ---------------- GAT: softmax + aggregate (+bias +ReLU), one wave per dst node ----------------
__global__ __launch_bounds__(256) void k_agg(const float* __restrict__ h, const float* __restrict__ as_,
                                             const float* __restrict__ ad_, const int* __restrict__ off,
                                             const int* __restrict__ sorted,
                                             const void* __restrict__ bias,
                                             const int* __restrict__ mode_p,
                                             float* __restrict__ out, int N) {
    int mode = *mode_p;
    int w = (blockIdx.x * blockDim.x + threadIdx.x) >> 6;
    int lane = threadIdx.x & 63;
    if (w >= N) return;
    int s0 = off[w], s1 = off[w + 1];
    float adv = ad_[w];
    float eself = lrelu(as_[w] + adv);
    float m = eself;
    for (int j = s0 + lane; j < s1; j += 64) {
        int s = clampi(sorted[j], 0, N - 1);
        m = fmaxf(m, lrelu(as_[s] + adv));
    }
#pragma unroll
    for (int d = 32; d > 0; d >>= 1) m = fmaxf(m, __shfl_xor(m, d, 64));
    const float2* h2 = (const float2*)h;
    float wself = __expf(eself - m);
    float denom = wself;
    float2 hv = h2[(size_t)w * 64 + lane];
    float a0 = wself * hv.x, a1 = wself * hv.y;
    for (int j = s0; j < s1; j++) {
        int s = clampi(sorted[j], 0, N - 1);
        float wj = __expf(lrelu(as_[s] + adv) - m);
        denom += wj;
        float2 hs = h2[(size_t)s * 64 + lane];
        a0 += wj * hs.x;
        a1 += wj * hs.y;
    }
    float inv = 1.f / fmaxf(denom, 1e-30f);
    float o0 = a0 * inv + ldm(bias, lane * 2, mode);
    float o1 = a1 * inv + ldm(bias, lane * 2 + 1, mode);
    out[(size_t)w * 128 + lane * 2] = fminf(fmaxf(o0, 0.f), 1e15f);
    out[(size_t)w * 128 + lane * 2 + 1] = fminf(fmaxf(o1, 0.f), 1e15f);
}

// ---------------- row norms ----------------
__global__ __launch_bounds__(256) void k_norm(const float* __restrict__ hr, float* __restrict__ rn, int N) {
    int w = (blockIdx.x * blockDim.x + threadIdx.x) >> 6;
    int lane = threadIdx.x & 63;
    if (w >= N) return;
    const float2* h2 = (const float2*)hr;
    float2 v = h2[(size_t)w * 64 + lane];
    float s = v.x * v.x + v.y * v.y;
#pragma unroll
    for (int d = 32; d > 0; d >>= 1) s += __shfl_xor(s, d, 64);
    if (lane == 0) rn[w] = s;
}

// ---------------- kNN partial: 64 colliders x chunk of resting ----------------
// ROUND-9 RESTRUCTURE (anti-spill): rounds 5-8 all spilled (~120-135 MB scratch
// writes/dispatch = the whole kernel time) because the scheduler software-
// pipelines the unrolled kk4 loop and hoists dozens of ds_read_b128 results,
// blowing any live-set budget; occupancy attributes didn't change that.
// Fix: 512 threads, 4x4 micro-tile (acc 16 + frags 32 + bv/bi 24 ~ 90 regs base)
// and "#pragma unroll 2" on kk4 (<=16 reads in flight) -> peak ~120 < 128 cap.
// tx = tid&15 (collider = c0 + tx + 16i, i<4), ty = tid>>4 (0..31; r = rt+ty+32j, j<4).
// Same 64x128 block tile, same LDS layout/stride. Per-(c,r) k-accumulation order
// unchanged (ks asc, kk4 asc, x,y,z,w) -> scores bit-identical; top-3 selection is
// partition-order independent, so NCH 12->6 re-chunking is selection-safe.
#define KNN_TC 64
#define KNN_TR 128
#define KNN_NCH 6
#define KNN_STRIDE 36

__global__ __launch_bounds__(512)
void k_knn_part(const float* __restrict__ hr,
                const float* __restrict__ hc,
                const float* __restrict__ rn,
                float* __restrict__ cand_v, int* __restrict__ cand_i,
                int NR, int NC, int chunk) {
    __shared__ float lds[(KNN_TC + KNN_TR) * KNN_STRIDE];  // 6912 floats = 27.6 KB
    float* hcs = lds;                          // [64][36]
    float* hrs = lds + KNN_TC * KNN_STRIDE;    // [128][36]
    int tid = threadIdx.x;   // 0..511
    int tx = tid & 15;       // 0..15
    int ty = tid >> 4;       // 0..31
    int c0 = blockIdx.x * KNN_TC;
    int rbase = blockIdx.y * chunk;
    int rend = min(rbase + chunk, NR);

    float bv[4][3];
    int bi[4][3];
#pragma unroll
    for (int i = 0; i < 4; i++)
#pragma unroll
        for (int j = 0; j < 3; j++) { bv[i][j] = 3.4e38f; bi[i][j] = 0x7fffffff; }

    for (int rt = rbase; rt < rend; rt += KNN_TR) {
        float acc[4][4];
#pragma unroll
        for (int i = 0; i < 4; i++)
#pragma unroll
            for (int j = 0; j < 4; j++) acc[i][j] = 0.f;

        for (int ks = 0; ks < 128; ks += 32) {
            __syncthreads();
            // stage hcs slab: 64 rows x 8 float4 = 512 items, 1 per thread
            {
                int row = tid >> 3, col4 = tid & 7;
                int c = c0 + row;
                float4 v = make_float4(0.f, 0.f, 0.f, 0.f);
                if (c < NC) v = *(const float4*)&hc[(size_t)c * 128 + ks + col4 * 4];
                *(float4*)&hcs[row * KNN_STRIDE + col4 * 4] = v;
            }
            // stage hrs slab: 128 rows x 8 float4 = 1024 items, 2 per thread
#pragma unroll
            for (int q = 0; q < 2; q++) {
                int idx = q * 512 + tid;
                int row = idx >> 3, col4 = idx & 7;
                int r = rt + row;
                float4 v = make_float4(0.f, 0.f, 0.f, 0.f);
                if (r < rend) v = *(const float4*)&hr[(size_t)r * 128 + ks + col4 * 4];
                *(float4*)&hrs[row * KNN_STRIDE + col4 * 4] = v;
            }
            __syncthreads();
#pragma unroll 2
            for (int kk4 = 0; kk4 < 8; kk4++) {
                float4 a[4], b[4];
#pragma unroll
                for (int i = 0; i < 4; i++)
                    a[i] = *(const float4*)&hcs[(tx + 16 * i) * KNN_STRIDE + kk4 * 4];
#pragma unroll
                for (int j = 0; j < 4; j++)
                    b[j] = *(const float4*)&hrs[(ty + 32 * j) * KNN_STRIDE + kk4 * 4];
#pragma unroll
                for (int i = 0; i < 4; i++)
#pragma unroll
                    for (int j = 0; j < 4; j++) {
                        acc[i][j] += a[i].x * b[j].x;
                        acc[i][j] += a[i].y * b[j].y;
                        acc[i][j] += a[i].z * b[j].z;
                        acc[i][j] += a[i].w * b[j].w;
                    }
            }
        }
        // score + top3 update (rank by rn[r] - 2*dot; per-collider |c|^2 constant irrelevant)
#pragma unroll
        for (int j = 0; j < 4; j++) {
            int r = rt + ty + 32 * j;
            if (r < rend) {
                float rnv = rn[r];
#pragma unroll
                for (int i = 0; i < 4; i++) {
                    float d = rnv - 2.f * acc[i][j];
                    ins3(d, r, bv[i], bi[i]);
                }
            }
        }
    }

    // two-pass merge across the 32 ty-groups (LDS scratch [64][48] fv + [64][48] fi = 24 KB)
    float* mv = lds;
    int* mi = (int*)(lds + KNN_TC * 48);
    float fv[3] = {3.4e38f, 3.4e38f, 3.4e38f};
    int fi[3] = {0x7fffffff, 0x7fffffff, 0x7fffffff};

    __syncthreads();
    if (ty < 16) {
#pragma unroll
        for (int i = 0; i < 4; i++) {
            int cc = tx + 16 * i;
#pragma unroll
            for (int j = 0; j < 3; j++) {
                mv[cc * 48 + ty * 3 + j] = bv[i][j];
                mi[cc * 48 + ty * 3 + j] = bi[i][j];
            }
        }
    }
    __syncthreads();
    if (tid < KNN_TC) {
        for (int t = 0; t < 48; t++) ins3(mv[tid * 48 + t], mi[tid * 48 + t], fv, fi);
    }
    __syncthreads();
    if (ty >= 16) {
#pragma unroll
        for (int i = 0; i < 4; i++) {
            int cc = tx + 16 * i;
#pragma unroll
            for (int j = 0; j < 3; j++) {
                mv[cc * 48 + (ty - 16) * 3 + j] = bv[i][j];
                mi[cc * 48 + (ty - 16) * 3 + j] = bi[i][j];
            }
        }
    }
    __syncthreads();
    if (tid < KNN_TC) {
        for (int t = 0; t < 48; t++) ins3(mv[tid * 48 + t], mi[tid * 48 + t], fv, fi);
        int c = c0 + tid;
        if (c < NC) {
            size_t o = ((size_t)c * KNN_NCH + blockIdx.y) * 3;
            cand_v[o + 0] = fv[0]; cand_i[o + 0] = fi[0];
            cand_v[o + 1] = fv[1]; cand_i[o + 1] = fi[1];
            cand_v[o + 2] = fv[2]; cand_i[o + 2] = fi[2];
        }
    }
}

__global__ void k_knn_merge(const float* __restrict__ cand_v, const int* __restrict__ cand_i,
                            int* __restrict__ knn, int NC, int NR) {
    int c = blockIdx.x * 256 + threadIdx.x;
    if (c >= NC) return;
    float fv[3] = {3.4e38f, 3.4e38f, 3.4e38f};
    int fi[3] = {0x7fffffff, 0x7fffffff, 0x7fffffff};
    size_t o = (size_t)c * KNN_NCH * 3;
    for (int t = 0; t < KNN_NCH * 3; t++) ins3(cand_v[o + t], cand_i[o + t], fv, fi);
    knn[c * 3 + 0] = clampi(fi[0], 0, NR - 1);
    knn[c * 3 + 1] = clampi(fi[1], 0, NR - 1);
    knn[c * 3 + 2] = clampi(fi[2], 0, NR - 1);
}

// ---------------- pooling scatter (mean via sums + counts) ----------------
__global__ __launch_bounds__(128) void k_pool_scatter(const float* __restrict__ hc,
                                                      const int* __restrict__ knn,
                                                      float* __restrict__ psum, float* __restrict__ pcnt,
                                                      int NC, int NR) {
    int c = blockIdx.x;
    int f = threadIdx.x;
    float v = hc[(size_t)c * 128 + f];
#pragma unroll
    for (int j = 0; j < 3; j++) {
        int r = clampi(knn[c * 3 + j], 0, NR - 1);
        atomicAdd(&psum[(size_t)r * 128 + f], v);
        if (f == 0) atomicAdd(&pcnt[r], 1.f);
    }
}

// ---------------- decode: out = [hr, pooled] @ Wd + bd ----------------
__global__ __launch_bounds__(256) void k_decode(const float* __restrict__ hr, const float* __restrict__ psum,
                                                const float* __restrict__ pcnt,
                                                const void* __restrict__ Wd,
                                                const void* __restrict__ bd,
                                                const int* __restrict__ mode_p,
                                                void* __restrict__ outv, int NR) {
    int mode = *mode_p;
    int w = (blockIdx.x * blockDim.x + threadIdx.x) >> 6;
    int lane = threadIdx.x & 63;
    if (w >= NR) return;
    float icnt = 1.f / fmaxf(pcnt[w], 1.f);
    float o0 = 0.f, o1 = 0.f, o2 = 0.f;
#pragma unroll
    for (int hh = 0; hh < 2; hh++) {
        int f = lane + hh * 64;
        float xv = hr[(size_t)w * 128 + f];
        o0 += xv * ldm(Wd, f * 3 + 0, mode);
        o1 += xv * ldm(Wd, f * 3 + 1, mode);
        o2 += xv * ldm(Wd, f * 3 + 2, mode);
        float pv = psum[(size_t)w * 128 + f] * icnt;
        o0 += pv * ldm(Wd, (128 + f) * 3 + 0, mode);
        o1 += pv * ldm(Wd, (128 + f) * 3 + 1, mode);
        o2 += pv * ldm(Wd, (128 + f) * 3 + 2, mode);
    }
#pragma unroll
    for (int d = 32; d > 0; d >>= 1) {
        o0 += __shfl_xor(o0, d, 64);
        o1 += __shfl_xor(o1, d, 64);
        o2 += __shfl_xor(o2, d, 64);
    }
    if (lane == 0) {
        float v0 = o0 + ldm(bd, 0, mode);
        float v1 = o1 + ldm(bd, 1, mode);
        float v2 = o2 + ldm(bd, 2, mode);
        if (mode) {
            float* out = (float*)outv;
            out[w * 3 + 0] = v0;
            out[w * 3 + 1] = v1;
            out[w * 3 + 2] = v2;
        } else {
            __hip_bfloat16* out = (__hip_bfloat16*)outv;
            out[w * 3 + 0] = __float2bfloat16(v0);
            out[w * 3 + 1] = __float2bfloat16(v1);
            out[w * 3 + 2] = __float2bfloat16(v2);
        }
    }
}

extern "C" void kernel_launch(void* const* d_in, const int* in_sizes, int n_in,
                              void* d_out, int out_size, void* d_ws, size_t ws_size,
                              hipStream_t stream) {
    const void* x_r = d_in[0];
    const int* ei_r = (const int*)d_in[1];
    const void* x_c = d_in[2];
    const int* ei_c = (const int*)d_in[3];
    const void* W1r = d_in[4];
    const void* as1r = d_in[5];
    const void* ad1r = d_in[6];
    const void* b1r = d_in[7];
    const void* W2r = d_in[8];
    const void* as2r = d_in[9];
    const void* ad2r = d_in[10];
    const void* b2r = d_in[11];
    const void* W1c = d_in[12];
    const void* as1c = d_in[13];
    const void* ad1c = d_in[14];
    const void* b1c = d_in[15];
    const void* W2c = d_in[16];
    const void* as2c = d_in[17];
    const void* ad2c = d_in[18];
    const void* b2c = d_in[19];
    const void* Wd = d_in[20];
    const void* bd = d_in[21];

    const int NR = in_sizes[0] / 3;
    const int ER = in_sizes[1] / 2;
    const int NC = in_sizes[2] / 6;
    const int EC = in_sizes[3] / 2;

    // ---- compact workspace layout with aliasing ----
    char* p = (char*)d_ws;
    size_t used = 0;
    auto alloc = [&](size_t bytes) {
        void* q = (void*)(p + used);
        used += (bytes + 255) & ~(size_t)255;
        return q;
    };
    float* r_A = (float*)alloc((size_t)NR * 128 * 4);  // h (resting); later psum
    float* r_B = (float*)alloc((size_t)NR * 128 * 4);  // x1 / final hr
    float* c_A = (float*)alloc((size_t)NC * 128 * 4);  // h (collider); later cand/knn
    float* c_B = (float*)alloc((size_t)NC * 128 * 4);  // x1 / final hc
    float* r_as = (float*)alloc((size_t)NR * 4);       // later rn
    float* r_ad = (float*)alloc((size_t)NR * 4);       // later pcnt
    float* c_as = (float*)alloc((size_t)NC * 4);
    float* c_ad = (float*)alloc((size_t)NC * 4);
    int* r_deg = (int*)alloc((size_t)NR * 4);
    int* r_cur = (int*)alloc((size_t)NR * 4);
    int* r_off = (int*)alloc((size_t)(NR + 1) * 4);
    int* r_sorted = (int*)alloc((size_t)ER * 4);
    int* c_deg = (int*)alloc((size_t)NC * 4);
    int* c_cur = (int*)alloc((size_t)NC * 4);
    int* c_off = (int*)alloc((size_t)(NC + 1) * 4);
    int* c_sorted = (int*)alloc((size_t)EC * 4);
    int* mode_p = (int*)alloc(256);

    // aliases (regions dead by the time these are used)
    float* psum = r_A;                       // dead after resting agg2
    float* rn = r_as;                        // dead after resting agg2
    float* pcnt = r_ad;                      // dead after resting agg2
    float* cand_v = c_A;                     // c_A dead after collider agg2
    int* cand_i = (int*)(c_A + (size_t)NC * KNN_NCH * 3);
    int* knn = (int*)(c_A + (size_t)NC * KNN_NCH * 6);

    if (ws_size < used) return;  // tripwire

    (void)hipMemsetAsync(r_deg, 0, (size_t)NR * 4, stream);
    (void)hipMemsetAsync(r_cur, 0, (size_t)NR * 4, stream);
    (void)hipMemsetAsync(c_deg, 0, (size_t)NC * 4, stream);
    (void)hipMemsetAsync(c_cur, 0, (size_t)NC * 4, stream);
    (void)hipMemsetAsync(mode_p, 0, 4, stream);

    // ---- dtype detect (bf16 vs fp32 storage of float tensors) ----
    k_detect<<<(in_sizes[0] + 255) / 256, 256, 0, stream>>>((const unsigned short*)x_r, in_sizes[0], mode_p);
    k_detect<<<(in_sizes[2] + 255) / 256, 256, 0, stream>>>((const unsigned short*)x_c, in_sizes[2], mode_p);

    // ---- sort edges by dst (once per graph, reused by both layers) ----
    k_hist<<<(ER + 255) / 256, 256, 0, stream>>>(ei_r + ER, ER, r_deg, NR);
    k_scan<<<1, 1024, 0, stream>>>(r_deg, r_off, NR);
    k_scatter<<<(ER + 255) / 256, 256, 0, stream>>>(ei_r, ei_r + ER, ER, r_off, r_cur, r_sorted, NR);
    k_hist<<<(EC + 255) / 256, 256, 0, stream>>>(ei_c + EC, EC, c_deg, NC);
    k_scan<<<1, 1024, 0, stream>>>(c_deg, c_off, NC);
    k_scatter<<<(EC + 255) / 256, 256, 0, stream>>>(ei_c, ei_c + EC, EC, c_off, c_cur, c_sorted, NC);

    const int aggBlocksR = (NR * 64 + 255) / 256;
    const int aggBlocksC = (NC * 64 + 255) / 256;

    // ---- resting branch: lin1 -> A, agg1 -> B, lin2(B) -> A, agg2 -> B (= hr) ----
    k_lin<3><<<NR, 128, 0, stream>>>(x_r, W1r, as1r, ad1r, mode_p, r_A, r_as, r_ad, NR);
    k_agg<<<aggBlocksR, 256, 0, stream>>>(r_A, r_as, r_ad, r_off, r_sorted, b1r, mode_p, r_B, NR);
    k_lin_f32<<<NR, 128, 0, stream>>>(r_B, W2r, as2r, ad2r, mode_p, r_A, r_as, r_ad, NR);
    k_agg<<<aggBlocksR, 256, 0, stream>>>(r_A, r_as, r_ad, r_off, r_sorted, b2r, mode_p, r_B, NR);

    // ---- collider branch ----
    k_lin<6><<<NC, 128, 0, stream>>>(x_c, W1c, as1c, ad1c, mode_p, c_A, c_as, c_ad, NC);
    k_agg<<<aggBlocksC, 256, 0, stream>>>(c_A, c_as, c_ad, c_off, c_sorted, b1c, mode_p, c_B, NC);
    k_lin_f32<<<NC, 128, 0, stream>>>(c_B, W2c, as2c, ad2c, mode_p, c_A, c_as, c_ad, NC);
    k_agg<<<aggBlocksC, 256, 0, stream>>>(c_A, c_as, c_ad, c_off, c_sorted, b2c, mode_p, c_B, NC);

    // r_A dead -> psum; zero mid-stream (stream-ordered, capture-safe)
    (void)hipMemsetAsync(psum, 0, (size_t)NR * 128 * 4, stream);
    (void)hipMemsetAsync(pcnt, 0, (size_t)NR * 4, stream);

    // ---- kNN + pooling ----
    k_norm<<<aggBlocksR, 256, 0, stream>>>(r_B, rn, NR);
    int chunk = (NR + KNN_NCH - 1) / KNN_NCH;
    dim3 kg((NC + KNN_TC - 1) / KNN_TC, KNN_NCH);
    k_knn_part<<<kg, 512, 0, stream>>>(r_B, c_B, rn, cand_v, cand_i, NR, NC, chunk);
    k_knn_merge<<<(NC + 255) / 256, 256, 0, stream>>>(cand_v, cand_i, knn, NC, NR);
    k_pool_scatter<<<NC, 128, 0, stream>>>(c_B, knn, psum, pcnt, NC, NR);

    // ---- decode ----
    k_decode<<<aggBlocksR, 256, 0, stream>>>(r_B, psum, pcnt, Wd, bd, mode_p, d_out, NR);
}

// Round 10
// 882.114 us; speedup vs baseline: 1.0768x; 1.0768x over previous
//
#include <hip/hip_runtime.h>
#include <hip/hip_bf16.h>
#include <cstdint>
#include <cstddef>

#define DI __device__ __forceinline__

DI float lrelu(float x) { return x > 0.f ? x : 0.2f * x; }
DI int clampi(int v, int lo, int hi) { return v < lo ? lo : (v > hi ? hi : v); }
DI float clampf(float v) { return fminf(fmaxf(v, -1e15f), 1e15f); }

// dual-mode load of a "float tensor": mode 0 = bf16 storage, mode 1 = fp32 storage
DI float ldm(const void* p, int i, int mode) {
    if (mode) return ((const float*)p)[i];
    return __bfloat162float(((const __hip_bfloat16*)p)[i]);
}

// better-than comparator: smaller value wins; tie -> smaller index (matches top_k)
DI void ins3(float v, int ix, float bv[3], int bi[3]) {
    bool b2 = (v < bv[2]) || (v == bv[2] && ix < bi[2]);
    if (!b2) return;
    bool b0 = (v < bv[0]) || (v == bv[0] && ix < bi[0]);
    bool b1 = (v < bv[1]) || (v == bv[1] && ix < bi[1]);
    if (b0) {
        bv[2] = bv[1]; bi[2] = bi[1];
        bv[1] = bv[0]; bi[1] = bi[0];
        bv[0] = v;     bi[0] = ix;
    } else if (b1) {
        bv[2] = bv[1]; bi[2] = bi[1];
        bv[1] = v;     bi[1] = ix;
    } else {
        bv[2] = v;     bi[2] = ix;
    }
}

// ---------------- dtype detection ----------------
__global__ void k_detect(const unsigned short* __restrict__ u, int n, int* __restrict__ flag) {
    int i = blockIdx.x * 256 + threadIdx.x;
    if (i < n) {
        if (((u[i] >> 7) & 0xFF) == 0xFF) atomicOr(flag, 1);
    }
}

// ---------------- edge sort (counting sort by dst) ----------------
__global__ void k_hist(const int* __restrict__ dst, int E, int* __restrict__ deg, int N) {
    int e = blockIdx.x * 256 + threadIdx.x;
    if (e < E) {
        unsigned d = (unsigned)dst[e];
        if (d < (unsigned)N) atomicAdd(&deg[d], 1);
    }
}

__global__ __launch_bounds__(1024) void k_scan(const int* __restrict__ deg, int* __restrict__ off, int N) {
    __shared__ int s[1024];
    __shared__ int carry_s;
    int tid = threadIdx.x;
    if (tid == 0) carry_s = 0;
    __syncthreads();
    for (int base = 0; base < N; base += 1024) {
        int i = base + tid;
        int v = (i < N) ? deg[i] : 0;
        s[tid] = v;
        __syncthreads();
        for (int d = 1; d < 1024; d <<= 1) {
            int t = (tid >= d) ? s[tid - d] : 0;
            __syncthreads();
            s[tid] += t;
            __syncthreads();
        }
        if (i < N) off[i] = carry_s + s[tid] - v;
        int tot = s[1023];
        __syncthreads();
        if (tid == 0) carry_s += tot;
        __syncthreads();
    }
    if (tid == 0) off[N] = carry_s;
}

__global__ void k_scatter(const int* __restrict__ src, const int* __restrict__ dst, int E,
                          const int* __restrict__ off, int* __restrict__ cur, int* __restrict__ sorted,
                          int N) {
    int e = blockIdx.x * 256 + threadIdx.x;
    if (e < E) {
        unsigned d = (unsigned)dst[e];
        if (d < (unsigned)N) {
            int p = off[d] + atomicAdd(&cur[d], 1);
            sorted[p] = clampi(src[e], 0, N - 1);
        }
    }
}

// ---------------- GAT: linear + attention scores (external input, dual-mode) ----------------
template <int FIN>
__global__ __launch_bounds__(128) void k_lin(const void* __restrict__ x,
                                             const void* __restrict__ W,
                                             const void* __restrict__ av_src,
                                             const void* __restrict__ av_dst,
                                             const int* __restrict__ mode_p,
                                             float* __restrict__ h, float* __restrict__ as_,
                                             float* __restrict__ ad_, int N) {
    int mode = *mode_p;
    int n = blockIdx.x;
    int f = threadIdx.x;
    __shared__ float xs[FIN];
    if (f < FIN) xs[f] = ldm(x, n * FIN + f, mode);
    __syncthreads();
    float acc = 0.f;
#pragma unroll
    for (int k = 0; k < FIN; k++) acc += xs[k] * ldm(W, k * 128 + f, mode);
    acc = clampf(acc);
    h[(size_t)n * 128 + f] = acc;
    __shared__ float r1[128], r2[128];
    r1[f] = acc * ldm(av_src, f, mode);
    r2[f] = acc * ldm(av_dst, f, mode);
    __syncthreads();
    for (int s2 = 64; s2 > 0; s2 >>= 1) {
        if (f < s2) { r1[f] += r1[f + s2]; r2[f] += r2[f + s2]; }
        __syncthreads();
    }
    if (f == 0) { as_[n] = clampf(r1[0]); ad_[n] = clampf(r2[0]); }
}

// ---------------- GAT layer-2 linear: INTERNAL fp32 input, dual-mode weights ----------------
__global__ __launch_bounds__(128) void k_lin_f32(const float* __restrict__ x,
                                                 const void* __restrict__ W,
                                                 const void* __restrict__ av_src,
                                                 const void* __restrict__ av_dst,
                                                 const int* __restrict__ mode_p,
                                                 float* __restrict__ h, float* __restrict__ as_,
                                                 float* __restrict__ ad_, int N) {
    int mode = *mode_p;
    int n = blockIdx.x;
    int f = threadIdx.x;
    __shared__ float xs[128];
    xs[f] = x[(size_t)n * 128 + f];
    __syncthreads();
    float acc = 0.f;
#pragma unroll
    for (int k = 0; k < 128; k++) acc += xs[k] * ldm(W, k * 128 + f, mode);
    acc = clampf(acc);
    h[(size_t)n * 128 + f] = acc;
    __shared__ float r1[128], r2[128];
    r1[f] = acc * ldm(av_src, f, mode);
    r2[f] = acc * ldm(av_dst, f, mode);
    __syncthreads();
    for (int s2 = 64; s2 > 0; s2 >>= 1) {
        if (f < s2) { r1[f] += r1[f + s2]; r2[f] += r2[f + s2]; }
        __syncthreads();
    }
    if (f == 0) { as_[n] = clampf(r1[0]); ad_[n] = clampf(r2[0]); }
}

// ---------------- GAT: softmax + aggregate (+bias +ReLU), one wave per dst node ----------------
__global__ __launch_bounds__(256) void k_agg(const float* __restrict__ h, const float* __restrict__ as_,
                                             const float* __restrict__ ad_, const int* __restrict__ off,
                                             const int* __restrict__ sorted,
                                             const void* __restrict__ bias,
                                             const int* __restrict__ mode_p,
                                             float* __restrict__ out, int N) {
    int mode = *mode_p;
    int w = (blockIdx.x * blockDim.x + threadIdx.x) >> 6;
    int lane = threadIdx.x & 63;
    if (w >= N) return;
    int s0 = off[w], s1 = off[w + 1];
    float adv = ad_[w];
    float eself = lrelu(as_[w] + adv);
    float m = eself;
    for (int j = s0 + lane; j < s1; j += 64) {
        int s = clampi(sorted[j], 0, N - 1);
        m = fmaxf(m, lrelu(as_[s] + adv));
    }
#pragma unroll
    for (int d = 32; d > 0; d >>= 1) m = fmaxf(m, __shfl_xor(m, d, 64));
    const float2* h2 = (const float2*)h;
    float wself = __expf(eself - m);
    float denom = wself;
    float2 hv = h2[(size_t)w * 64 + lane];
    float a0 = wself * hv.x, a1 = wself * hv.y;
    for (int j = s0; j < s1; j++) {
        int s = clampi(sorted[j], 0, N - 1);
        float wj = __expf(lrelu(as_[s] + adv) - m);
        denom += wj;
        float2 hs = h2[(size_t)s * 64 + lane];
        a0 += wj * hs.x;
        a1 += wj * hs.y;
    }
    float inv = 1.f / fmaxf(denom, 1e-30f);
    float o0 = a0 * inv + ldm(bias, lane * 2, mode);
    float o1 = a1 * inv + ldm(bias, lane * 2 + 1, mode);
    out[(size_t)w * 128 + lane * 2] = fminf(fmaxf(o0, 0.f), 1e15f);
    out[(size_t)w * 128 + lane * 2 + 1] = fminf(fmaxf(o1, 0.f), 1e15f);
}

// ---------------- row norms ----------------
__global__ __launch_bounds__(256) void k_norm(const float* __restrict__ hr, float* __restrict__ rn, int N) {
    int w = (blockIdx.x * blockDim.x + threadIdx.x) >> 6;
    int lane = threadIdx.x & 63;
    if (w >= N) return;
    const float2* h2 = (const float2*)hr;
    float2 v = h2[(size_t)w * 64 + lane];
    float s = v.x * v.x + v.y * v.y;
#pragma unroll
    for (int d = 32; d > 0; d >>= 1) s += __shfl_xor(s, d, 64);
    if (lane == 0) rn[w] = s;
}

// ---------------- kNN partial: 64 colliders x chunk of resting ----------------
// ROUND-10: combine the two verified facts:
//  (a) 8x4 micro-tile @256 threads has the right compute:LDS ratio (1.5 B/FMA;
//      4x4 @512 was 2 B/FMA -> LDS ceiling capped VALU at ~50%, round 9).
//  (b) "#pragma unroll 2" on kk4 bounds the scheduler's load hoisting, which
//      is what caused the 120-135 MB scratch spill in rounds 5-8 (full unroll).
//      Round 9 proof: 4x4 + unroll 2 -> 68 VGPR, WRITE_SIZE 2.3 MB (no spill).
// tx = tid&7 (collider = c0 + tx + 8i, i<8), ty = tid>>3 (0..31; r = rt+ty+32j, j<4).
// NCH=16: 79x16 = 1264 blocks vs 5 blocks/CU (LDS 27.6 KB) x 256 = 1280 -> one wave.
// Per-(c,r) k-accumulation order unchanged (ks asc, kk4 asc, x,y,z,w; unroll
// does not reorder within a chain) -> scores bit-identical (round 9: absmax 0.0).
#define KNN_TC 64
#define KNN_TR 128
#define KNN_NCH 16
#define KNN_STRIDE 36

__global__ __launch_bounds__(256)
void k_knn_part(const float* __restrict__ hr,
                const float* __restrict__ hc,
                const float* __restrict__ rn,
                float* __restrict__ cand_v, int* __restrict__ cand_i,
                int NR, int NC, int chunk) {
    __shared__ float lds[(KNN_TC + KNN_TR) * KNN_STRIDE];  // 6912 floats = 27.6 KB
    float* hcs = lds;                          // [64][36]
    float* hrs = lds + KNN_TC * KNN_STRIDE;    // [128][36]
    int tid = threadIdx.x;   // 0..255
    int tx = tid & 7;        // 0..7
    int ty = tid >> 3;       // 0..31
    int c0 = blockIdx.x * KNN_TC;
    int rbase = blockIdx.y * chunk;
    int rend = min(rbase + chunk, NR);

    float bv[8][3];
    int bi[8][3];
#pragma unroll
    for (int i = 0; i < 8; i++)
#pragma unroll
        for (int j = 0; j < 3; j++) { bv[i][j] = 3.4e38f; bi[i][j] = 0x7fffffff; }

    for (int rt = rbase; rt < rend; rt += KNN_TR) {
        float acc[8][4];
#pragma unroll
        for (int i = 0; i < 8; i++)
#pragma unroll
            for (int j = 0; j < 4; j++) acc[i][j] = 0.f;

        for (int ks = 0; ks < 128; ks += 32) {
            __syncthreads();
            // stage hcs slab: 64 rows x 8 float4 = 512 items / 256 threads
#pragma unroll
            for (int q = 0; q < 2; q++) {
                int idx = q * 256 + tid;
                int row = idx >> 3, col4 = idx & 7;
                int c = c0 + row;
                float4 v = make_float4(0.f, 0.f, 0.f, 0.f);
                if (c < NC) v = *(const float4*)&hc[(size_t)c * 128 + ks + col4 * 4];
                *(float4*)&hcs[row * KNN_STRIDE + col4 * 4] = v;
            }
            // stage hrs slab: 128 rows x 8 float4 = 1024 items / 256 threads
#pragma unroll
            for (int q = 0; q < 4; q++) {
                int idx = q * 256 + tid;
                int row = idx >> 3, col4 = idx & 7;
                int r = rt + row;
                float4 v = make_float4(0.f, 0.f, 0.f, 0.f);
                if (r < rend) v = *(const float4*)&hr[(size_t)r * 128 + ks + col4 * 4];
                *(float4*)&hrs[row * KNN_STRIDE + col4 * 4] = v;
            }
            __syncthreads();
#pragma unroll 2
            for (int kk4 = 0; kk4 < 8; kk4++) {
                float4 b[4];
#pragma unroll
                for (int j = 0; j < 4; j++)
                    b[j] = *(const float4*)&hrs[(ty + 32 * j) * KNN_STRIDE + kk4 * 4];
#pragma unroll
                for (int i = 0; i < 8; i++) {
                    float4 a = *(const float4*)&hcs[(tx + 8 * i) * KNN_STRIDE + kk4 * 4];
#pragma unroll
                    for (int j = 0; j < 4; j++) {
                        acc[i][j] += a.x * b[j].x;
                        acc[i][j] += a.y * b[j].y;
                        acc[i][j] += a.z * b[j].z;
                        acc[i][j] += a.w * b[j].w;
                    }
                }
            }
        }
        // score + top3 update (rank by rn[r] - 2*dot; per-collider |c|^2 constant irrelevant)
#pragma unroll
        for (int j = 0; j < 4; j++) {
            int r = rt + ty + 32 * j;
            if (r < rend) {
                float rnv = rn[r];
#pragma unroll
                for (int i = 0; i < 8; i++) {
                    float d = rnv - 2.f * acc[i][j];
                    ins3(d, r, bv[i], bi[i]);
                }
            }
        }
    }

    // two-pass merge across the 32 ty-groups (LDS scratch [64][48] fv + [64][48] fi = 24 KB)
    float* mv = lds;
    int* mi = (int*)(lds + KNN_TC * 48);
    float fv[3] = {3.4e38f, 3.4e38f, 3.4e38f};
    int fi[3] = {0x7fffffff, 0x7fffffff, 0x7fffffff};

    __syncthreads();
    if (ty < 16) {
#pragma unroll
        for (int i = 0; i < 8; i++) {
            int cc = tx + 8 * i;
#pragma unroll
            for (int j = 0; j < 3; j++) {
                mv[cc * 48 + ty * 3 + j] = bv[i][j];
                mi[cc * 48 + ty * 3 + j] = bi[i][j];
            }
        }
    }
    __syncthreads();
    if (tid < KNN_TC) {
        for (int t = 0; t < 48; t++) ins3(mv[tid * 48 + t], mi[tid * 48 + t], fv, fi);
    }
    __syncthreads();
    if (ty >= 16) {
#pragma unroll
        for (int i = 0; i < 8; i++) {
            int cc = tx + 8 * i;
#pragma unroll
            for (int j = 0; j < 3; j++) {
                mv[cc * 48 + (ty - 16) * 3 + j] = bv[i][j];
                mi[cc * 48 + (ty - 16) * 3 + j] = bi[i][j];
            }
        }
    }
    __syncthreads();
    if (tid < KNN_TC) {
        for (int t = 0; t < 48; t++) ins3(mv[tid * 48 + t], mi[tid * 48 + t], fv, fi);
        int c = c0 + tid;
        if (c < NC) {
            size_t o = ((size_t)c * KNN_NCH + blockIdx.y) * 3;
            cand_v[o + 0] = fv[0]; cand_i[o + 0] = fi[0];
            cand_v[o + 1] = fv[1]; cand_i[o + 1] = fi[1];
            cand_v[o + 2] = fv[2]; cand_i[o + 2] = fi[2];
        }
    }
}

__global__ void k_knn_merge(const float* __restrict__ cand_v, const int* __restrict__ cand_i,
                            int* __restrict__ knn, int NC, int NR) {
    int c = blockIdx.x * 256 + threadIdx.x;
    if (c >= NC) return;
    float fv[3] = {3.4e38f, 3.4e38f, 3.4e38f};
    int fi[3] = {0x7fffffff, 0x7fffffff, 0x7fffffff};
    size_t o = (size_t)c * KNN_NCH * 3;
    for (int t = 0; t < KNN_NCH * 3; t++) ins3(cand_v[o + t], cand_i[o + t], fv, fi);
    knn[c * 3 + 0] = clampi(fi[0], 0, NR - 1);
    knn[c * 3 + 1] = clampi(fi[1], 0, NR - 1);
    knn[c * 3 + 2] = clampi(fi[2], 0, NR - 1);
}

// ---------------- pooling scatter (mean via sums + counts) ----------------
__global__ __launch_bounds__(128) void k_pool_scatter(const float* __restrict__ hc,
                                                      const int* __restrict__ knn,
                                                      float* __restrict__ psum, float* __restrict__ pcnt,
                                                      int NC, int NR) {
    int c = blockIdx.x;
    int f = threadIdx.x;
    float v = hc[(size_t)c * 128 + f];
#pragma unroll
    for (int j = 0; j < 3; j++) {
        int r = clampi(knn[c * 3 + j], 0, NR - 1);
        atomicAdd(&psum[(size_t)r * 128 + f], v);
        if (f == 0) atomicAdd(&pcnt[r], 1.f);
    }
}

// ---------------- decode: out = [hr, pooled] @ Wd + bd ----------------
__global__ __launch_bounds__(256) void k_decode(const float* __restrict__ hr, const float* __restrict__ psum,
                                                const float* __restrict__ pcnt,
                                                const void* __restrict__ Wd,
                                                const void* __restrict__ bd,
                                                const int* __restrict__ mode_p,
                                                void* __restrict__ outv, int NR) {
    int mode = *mode_p;
    int w = (blockIdx.x * blockDim.x + threadIdx.x) >> 6;
    int lane = threadIdx.x & 63;
    if (w >= NR) return;
    float icnt = 1.f / fmaxf(pcnt[w], 1.f);
    float o0 = 0.f, o1 = 0.f, o2 = 0.f;
#pragma unroll
    for (int hh = 0; hh < 2; hh++) {
        int f = lane + hh * 64;
        float xv = hr[(size_t)w * 128 + f];
        o0 += xv * ldm(Wd, f * 3 + 0, mode);
        o1 += xv * ldm(Wd, f * 3 + 1, mode);
        o2 += xv * ldm(Wd, f * 3 + 2, mode);
        float pv = psum[(size_t)w * 128 + f] * icnt;
        o0 += pv * ldm(Wd, (128 + f) * 3 + 0, mode);
        o1 += pv * ldm(Wd, (128 + f) * 3 + 1, mode);
        o2 += pv * ldm(Wd, (128 + f) * 3 + 2, mode);
    }
#pragma unroll
    for (int d = 32; d > 0; d >>= 1) {
        o0 += __shfl_xor(o0, d, 64);
        o1 += __shfl_xor(o1, d, 64);
        o2 += __shfl_xor(o2, d, 64);
    }
    if (lane == 0) {
        float v0 = o0 + ldm(bd, 0, mode);
        float v1 = o1 + ldm(bd, 1, mode);
        float v2 = o2 + ldm(bd, 2, mode);
        if (mode) {
            float* out = (float*)outv;
            out[w * 3 + 0] = v0;
            out[w * 3 + 1] = v1;
            out[w * 3 + 2] = v2;
        } else {
            __hip_bfloat16* out = (__hip_bfloat16*)outv;
            out[w * 3 + 0] = __float2bfloat16(v0);
            out[w * 3 + 1] = __float2bfloat16(v1);
            out[w * 3 + 2] = __float2bfloat16(v2);
        }
    }
}

extern "C" void kernel_launch(void* const* d_in, const int* in_sizes, int n_in,
                              void* d_out, int out_size, void* d_ws, size_t ws_size,
                              hipStream_t stream) {
    const void* x_r = d_in[0];
    const int* ei_r = (const int*)d_in[1];
    const void* x_c = d_in[2];
    const int* ei_c = (const int*)d_in[3];
    const void* W1r = d_in[4];
    const void* as1r = d_in[5];
    const void* ad1r = d_in[6];
    const void* b1r = d_in[7];
    const void* W2r = d_in[8];
    const void* as2r = d_in[9];
    const void* ad2r = d_in[10];
    const void* b2r = d_in[11];
    const void* W1c = d_in[12];
    const void* as1c = d_in[13];
    const void* ad1c = d_in[14];
    const void* b1c = d_in[15];
    const void* W2c = d_in[16];
    const void* as2c = d_in[17];
    const void* ad2c = d_in[18];
    const void* b2c = d_in[19];
    const void* Wd = d_in[20];
    const void* bd = d_in[21];

    const int NR = in_sizes[0] / 3;
    const int ER = in_sizes[1] / 2;
    const int NC = in_sizes[2] / 6;
    const int EC = in_sizes[3] / 2;

    // ---- compact workspace layout with aliasing ----
    char* p = (char*)d_ws;
    size_t used = 0;
    auto alloc = [&](size_t bytes) {
        void* q = (void*)(p + used);
        used += (bytes + 255) & ~(size_t)255;
        return q;
    };
    float* r_A = (float*)alloc((size_t)NR * 128 * 4);  // h (resting); later psum
    float* r_B = (float*)alloc((size_t)NR * 128 * 4);  // x1 / final hr
    float* c_A = (float*)alloc((size_t)NC * 128 * 4);  // h (collider); later cand/knn
    float* c_B = (float*)alloc((size_t)NC * 128 * 4);  // x1 / final hc
    float* r_as = (float*)alloc((size_t)NR * 4);       // later rn
    float* r_ad = (float*)alloc((size_t)NR * 4);       // later pcnt
    float* c_as = (float*)alloc((size_t)NC * 4);
    float* c_ad = (float*)alloc((size_t)NC * 4);
    int* r_deg = (int*)alloc((size_t)NR * 4);
    int* r_cur = (int*)alloc((size_t)NR * 4);
    int* r_off = (int*)alloc((size_t)(NR + 1) * 4);
    int* r_sorted = (int*)alloc((size_t)ER * 4);
    int* c_deg = (int*)alloc((size_t)NC * 4);
    int* c_cur = (int*)alloc((size_t)NC * 4);
    int* c_off = (int*)alloc((size_t)(NC + 1) * 4);
    int* c_sorted = (int*)alloc((size_t)EC * 4);
    int* mode_p = (int*)alloc(256);

    // aliases (regions dead by the time these are used)
    float* psum = r_A;                       // dead after resting agg2
    float* rn = r_as;                        // dead after resting agg2
    float* pcnt = r_ad;                      // dead after resting agg2
    float* cand_v = c_A;                     // c_A dead after collider agg2
    int* cand_i = (int*)(c_A + (size_t)NC * KNN_NCH * 3);
    int* knn = (int*)(c_A + (size_t)NC * KNN_NCH * 6);

    if (ws_size < used) return;  // tripwire

    (void)hipMemsetAsync(r_deg, 0, (size_t)NR * 4, stream);
    (void)hipMemsetAsync(r_cur, 0, (size_t)NR * 4, stream);
    (void)hipMemsetAsync(c_deg, 0, (size_t)NC * 4, stream);
    (void)hipMemsetAsync(c_cur, 0, (size_t)NC * 4, stream);
    (void)hipMemsetAsync(mode_p, 0, 4, stream);

    // ---- dtype detect (bf16 vs fp32 storage of float tensors) ----
    k_detect<<<(in_sizes[0] + 255) / 256, 256, 0, stream>>>((const unsigned short*)x_r, in_sizes[0], mode_p);
    k_detect<<<(in_sizes[2] + 255) / 256, 256, 0, stream>>>((const unsigned short*)x_c, in_sizes[2], mode_p);

    // ---- sort edges by dst (once per graph, reused by both layers) ----
    k_hist<<<(ER + 255) / 256, 256, 0, stream>>>(ei_r + ER, ER, r_deg, NR);
    k_scan<<<1, 1024, 0, stream>>>(r_deg, r_off, NR);
    k_scatter<<<(ER + 255) / 256, 256, 0, stream>>>(ei_r, ei_r + ER, ER, r_off, r_cur, r_sorted, NR);
    k_hist<<<(EC + 255) / 256, 256, 0, stream>>>(ei_c + EC, EC, c_deg, NC);
    k_scan<<<1, 1024, 0, stream>>>(c_deg, c_off, NC);
    k_scatter<<<(EC + 255) / 256, 256, 0, stream>>>(ei_c, ei_c + EC, EC, c_off, c_cur, c_sorted, NC);

    const int aggBlocksR = (NR * 64 + 255) / 256;
    const int aggBlocksC = (NC * 64 + 255) / 256;

    // ---- resting branch: lin1 -> A, agg1 -> B, lin2(B) -> A, agg2 -> B (= hr) ----
    k_lin<3><<<NR, 128, 0, stream>>>(x_r, W1r, as1r, ad1r, mode_p, r_A, r_as, r_ad, NR);
    k_agg<<<aggBlocksR, 256, 0, stream>>>(r_A, r_as, r_ad, r_off, r_sorted, b1r, mode_p, r_B, NR);
    k_lin_f32<<<NR, 128, 0, stream>>>(r_B, W2r, as2r, ad2r, mode_p, r_A, r_as, r_ad, NR);
    k_agg<<<aggBlocksR, 256, 0, stream>>>(r_A, r_as, r_ad, r_off, r_sorted, b2r, mode_p, r_B, NR);

    // ---- collider branch ----
    k_lin<6><<<NC, 128, 0, stream>>>(x_c, W1c, as1c, ad1c, mode_p, c_A, c_as, c_ad, NC);
    k_agg<<<aggBlocksC, 256, 0, stream>>>(c_A, c_as, c_ad, c_off, c_sorted, b1c, mode_p, c_B, NC);
    k_lin_f32<<<NC, 128, 0, stream>>>(c_B, W2c, as2c, ad2c, mode_p, c_A, c_as, c_ad, NC);
    k_agg<<<aggBlocksC, 256, 0, stream>>>(c_A, c_as, c_ad, c_off, c_sorted, b2c, mode_p, c_B, NC);

    // r_A dead -> psum; zero mid-stream (stream-ordered, capture-safe)
    (void)hipMemsetAsync(psum, 0, (size_t)NR * 128 * 4, stream);
    (void)hipMemsetAsync(pcnt, 0, (size_t)NR * 4, stream);

    // ---- kNN + pooling ----
    k_norm<<<aggBlocksR, 256, 0, stream>>>(r_B, rn, NR);
    int chunk = (NR + KNN_NCH - 1) / KNN_NCH;
    dim3 kg((NC + KNN_TC - 1) / KNN_TC, KNN_NCH);
    k_knn_part<<<kg, 256, 0, stream>>>(r_B, c_B, rn, cand_v, cand_i, NR, NC, chunk);
    k_knn_merge<<<(NC + 255) / 256, 256, 0, stream>>>(cand_v, cand_i, knn, NC, NR);
    k_pool_scatter<<<NC, 128, 0, stream>>>(c_B, knn, psum, pcnt, NC, NR);

    // ---- decode ----
    k_decode<<<aggBlocksR, 256, 0, stream>>>(r_B, psum, pcnt, Wd, bd, mode_p, d_out, NR);
}

// Round 11
// 803.615 us; speedup vs baseline: 1.1820x; 1.0977x over previous
//
#include <hip/hip_runtime.h>
#include <hip/hip_bf16.h>
#include <cstdint>
#include <cstddef>

#define DI __device__ __forceinline__

DI float lrelu(float x) { return x > 0.f ? x : 0.2f * x; }
DI int clampi(int v, int lo, int hi) { return v < lo ? lo : (v > hi ? hi : v); }
DI float clampf(float v) { return fminf(fmaxf(v, -1e15f), 1e15f); }

// dual-mode load of a "float tensor": mode 0 = bf16 storage, mode 1 = fp32 storage
DI float ldm(const void* p, int i, int mode) {
    if (mode) return ((const float*)p)[i];
    return __bfloat162float(((const __hip_bfloat16*)p)[i]);
}

// better-than comparator: smaller value wins; tie -> smaller index (matches top_k)
DI void ins3(float v, int ix, float bv[3], int bi[3]) {
    bool b2 = (v < bv[2]) || (v == bv[2] && ix < bi[2]);
    if (!b2) return;
    bool b0 = (v < bv[0]) || (v == bv[0] && ix < bi[0]);
    bool b1 = (v < bv[1]) || (v == bv[1] && ix < bi[1]);
    if (b0) {
        bv[2] = bv[1]; bi[2] = bi[1];
        bv[1] = bv[0]; bi[1] = bi[0];
        bv[0] = v;     bi[0] = ix;
    } else if (b1) {
        bv[2] = bv[1]; bi[2] = bi[1];
        bv[1] = v;     bi[1] = ix;
    } else {
        bv[2] = v;     bi[2] = ix;
    }
}

// ---------------- fused dtype detection (both tensors, one launch) ----------------
__global__ void k_detect2(const unsigned short* __restrict__ u0, int n0,
                          const unsigned short* __restrict__ u1, int n1,
                          int* __restrict__ flag) {
    int i = blockIdx.x * 256 + threadIdx.x;
    if (i < n0 + n1) {
        unsigned short v = (i < n0) ? u0[i] : u1[i - n0];
        if (((v >> 7) & 0xFF) == 0xFF) atomicOr(flag, 1);
    }
}

// ---------------- fused edge hist/scan/scatter (both graphs) ----------------
__global__ void k_hist2(const int* __restrict__ dstR, int ER, int* __restrict__ degR, int NR,
                        const int* __restrict__ dstC, int EC, int* __restrict__ degC, int NC) {
    int e = blockIdx.x * 256 + threadIdx.x;
    if (e < ER) {
        unsigned d = (unsigned)dstR[e];
        if (d < (unsigned)NR) atomicAdd(&degR[d], 1);
    } else if (e < ER + EC) {
        unsigned d = (unsigned)dstC[e - ER];
        if (d < (unsigned)NC) atomicAdd(&degC[d], 1);
    }
}

__global__ __launch_bounds__(1024) void k_scan2(const int* __restrict__ degR, int* __restrict__ offR, int NR,
                                                const int* __restrict__ degC, int* __restrict__ offC, int NC) {
    const int* deg = blockIdx.x ? degC : degR;
    int* off = blockIdx.x ? offC : offR;
    int N = blockIdx.x ? NC : NR;
    __shared__ int s[1024];
    __shared__ int carry_s;
    int tid = threadIdx.x;
    if (tid == 0) carry_s = 0;
    __syncthreads();
    for (int base = 0; base < N; base += 1024) {
        int i = base + tid;
        int v = (i < N) ? deg[i] : 0;
        s[tid] = v;
        __syncthreads();
        for (int d = 1; d < 1024; d <<= 1) {
            int t = (tid >= d) ? s[tid - d] : 0;
            __syncthreads();
            s[tid] += t;
            __syncthreads();
        }
        if (i < N) off[i] = carry_s + s[tid] - v;
        int tot = s[1023];
        __syncthreads();
        if (tid == 0) carry_s += tot;
        __syncthreads();
    }
    if (tid == 0) off[N] = carry_s;
}

__global__ void k_scatter2(const int* __restrict__ srcR, const int* __restrict__ dstR, int ER,
                           const int* __restrict__ offR, int* __restrict__ curR, int* __restrict__ sortedR, int NR,
                           const int* __restrict__ srcC, const int* __restrict__ dstC, int EC,
                           const int* __restrict__ offC, int* __restrict__ curC, int* __restrict__ sortedC, int NC) {
    int e = blockIdx.x * 256 + threadIdx.x;
    if (e < ER) {
        unsigned d = (unsigned)dstR[e];
        if (d < (unsigned)NR) {
            int p = offR[d] + atomicAdd(&curR[d], 1);
            sortedR[p] = clampi(srcR[e], 0, NR - 1);
        }
    } else if (e < ER + EC) {
        int e2 = e - ER;
        unsigned d = (unsigned)dstC[e2];
        if (d < (unsigned)NC) {
            int p = offC[d] + atomicAdd(&curC[d], 1);
            sortedC[p] = clampi(srcC[e2], 0, NC - 1);
        }
    }
}

// ---------------- fused layer-1 linear (resting FIN=3 + collider FIN=6) ----------------
__global__ __launch_bounds__(128) void k_lin1_both(
    const void* __restrict__ xR, const void* __restrict__ WR,
    const void* __restrict__ avsR, const void* __restrict__ avdR,
    float* __restrict__ hR, float* __restrict__ asR, float* __restrict__ adR, int NR,
    const void* __restrict__ xC, const void* __restrict__ WC,
    const void* __restrict__ avsC, const void* __restrict__ avdC,
    float* __restrict__ hC, float* __restrict__ asC, float* __restrict__ adC, int NC,
    const int* __restrict__ mode_p) {
    int mode = *mode_p;
    int bid = blockIdx.x;
    int f = threadIdx.x;
    const void *x, *W, *avs, *avd;
    float *h, *as_, *ad_;
    int n, fin;
    if (bid < NR) { n = bid; fin = 3; x = xR; W = WR; avs = avsR; avd = avdR; h = hR; as_ = asR; ad_ = adR; }
    else          { n = bid - NR; fin = 6; x = xC; W = WC; avs = avsC; avd = avdC; h = hC; as_ = asC; ad_ = adC; }
    __shared__ float xs[8];
    __shared__ float r1[128], r2[128];
    if (f < fin) xs[f] = ldm(x, n * fin + f, mode);
    __syncthreads();
    float acc = 0.f;
    for (int k = 0; k < fin; k++) acc += xs[k] * ldm(W, k * 128 + f, mode);
    acc = clampf(acc);
    h[(size_t)n * 128 + f] = acc;
    r1[f] = acc * ldm(avs, f, mode);
    r2[f] = acc * ldm(avd, f, mode);
    __syncthreads();
    for (int s2 = 64; s2 > 0; s2 >>= 1) {
        if (f < s2) { r1[f] += r1[f + s2]; r2[f] += r2[f + s2]; }
        __syncthreads();
    }
    if (f == 0) { as_[n] = clampf(r1[0]); ad_[n] = clampf(r2[0]); }
}

// ---------------- fused layer-2 linear (both branches, fp32 input) ----------------
__global__ __launch_bounds__(128) void k_lin2_both(
    const float* __restrict__ xR, const void* __restrict__ WR,
    const void* __restrict__ avsR, const void* __restrict__ avdR,
    float* __restrict__ hR, float* __restrict__ asR, float* __restrict__ adR, int NR,
    const float* __restrict__ xC, const void* __restrict__ WC,
    const void* __restrict__ avsC, const void* __restrict__ avdC,
    float* __restrict__ hC, float* __restrict__ asC, float* __restrict__ adC, int NC,
    const int* __restrict__ mode_p) {
    int mode = *mode_p;
    int bid = blockIdx.x;
    int f = threadIdx.x;
    const float* x;
    const void *W, *avs, *avd;
    float *h, *as_, *ad_;
    int n;
    if (bid < NR) { n = bid; x = xR; W = WR; avs = avsR; avd = avdR; h = hR; as_ = asR; ad_ = adR; }
    else          { n = bid - NR; x = xC; W = WC; avs = avsC; avd = avdC; h = hC; as_ = asC; ad_ = adC; }
    __shared__ float xs[128];
    __shared__ float r1[128], r2[128];
    xs[f] = x[(size_t)n * 128 + f];
    __syncthreads();
    float acc = 0.f;
#pragma unroll
    for (int k = 0; k < 128; k++) acc += xs[k] * ldm(W, k * 128 + f, mode);
    acc = clampf(acc);
    h[(size_t)n * 128 + f] = acc;
    r1[f] = acc * ldm(avs, f, mode);
    r2[f] = acc * ldm(avd, f, mode);
    __syncthreads();
    for (int s2 = 64; s2 > 0; s2 >>= 1) {
        if (f < s2) { r1[f] += r1[f + s2]; r2[f] += r2[f + s2]; }
        __syncthreads();
    }
    if (f == 0) { as_[n] = clampf(r1[0]); ad_[n] = clampf(r2[0]); }
}

// ---------------- fused softmax-aggregate (both branches; optional rn epilogue) ----------------
// Body identical to prior k_agg (same summation order). do_rn=1: resting part also
// writes rn[w] = sum of squared outputs (replaces the separate k_norm launch).
__global__ __launch_bounds__(256) void k_agg_both(
    const float* __restrict__ hR, const float* __restrict__ asR, const float* __restrict__ adR,
    const int* __restrict__ offR, const int* __restrict__ srtR, const void* __restrict__ biasR,
    float* __restrict__ outR, int NR,
    const float* __restrict__ hC, const float* __restrict__ asC, const float* __restrict__ adC,
    const int* __restrict__ offC, const int* __restrict__ srtC, const void* __restrict__ biasC,
    float* __restrict__ outC, int NC,
    const int* __restrict__ mode_p, int blocksR, float* __restrict__ rn, int do_rn) {
    int mode = *mode_p;
    int bid = blockIdx.x;
    int wid = threadIdx.x >> 6;
    int lane = threadIdx.x & 63;
    const float *h, *as_, *ad_;
    const int *off, *sorted;
    const void* bias;
    float* out;
    int w, N, isR;
    if (bid < blocksR) { isR = 1; w = bid * 4 + wid; N = NR; h = hR; as_ = asR; ad_ = adR; off = offR; sorted = srtR; bias = biasR; out = outR; }
    else               { isR = 0; w = (bid - blocksR) * 4 + wid; N = NC; h = hC; as_ = asC; ad_ = adC; off = offC; sorted = srtC; bias = biasC; out = outC; }
    if (w >= N) return;
    int s0 = off[w], s1 = off[w + 1];
    float adv = ad_[w];
    float eself = lrelu(as_[w] + adv);
    float m = eself;
    for (int j = s0 + lane; j < s1; j += 64) {
        int s = clampi(sorted[j], 0, N - 1);
        m = fmaxf(m, lrelu(as_[s] + adv));
    }
#pragma unroll
    for (int d = 32; d > 0; d >>= 1) m = fmaxf(m, __shfl_xor(m, d, 64));
    const float2* h2 = (const float2*)h;
    float wself = __expf(eself - m);
    float denom = wself;
    float2 hv = h2[(size_t)w * 64 + lane];
    float a0 = wself * hv.x, a1 = wself * hv.y;
    for (int j = s0; j < s1; j++) {
        int s = clampi(sorted[j], 0, N - 1);
        float wj = __expf(lrelu(as_[s] + adv) - m);
        denom += wj;
        float2 hs = h2[(size_t)s * 64 + lane];
        a0 += wj * hs.x;
        a1 += wj * hs.y;
    }
    float inv = 1.f / fmaxf(denom, 1e-30f);
    float o0 = fminf(fmaxf(a0 * inv + ldm(bias, lane * 2, mode), 0.f), 1e15f);
    float o1 = fminf(fmaxf(a1 * inv + ldm(bias, lane * 2 + 1, mode), 0.f), 1e15f);
    out[(size_t)w * 128 + lane * 2] = o0;
    out[(size_t)w * 128 + lane * 2 + 1] = o1;
    if (do_rn && isR) {
        float s = o0 * o0 + o1 * o1;
#pragma unroll
        for (int d = 32; d > 0; d >>= 1) s += __shfl_xor(s, d, 64);
        if (lane == 0) rn[w] = s;
    }
}

// ---------------- kNN partial (UNCHANGED from round 10: 8x4 @256thr, unroll 2) ----------------
#define KNN_TC 64
#define KNN_TR 128
#define KNN_NCH 16
#define KNN_STRIDE 36

__global__ __launch_bounds__(256)
void k_knn_part(const float* __restrict__ hr,
                const float* __restrict__ hc,
                const float* __restrict__ rn,
                float* __restrict__ cand_v, int* __restrict__ cand_i,
                int NR, int NC, int chunk) {
    __shared__ float lds[(KNN_TC + KNN_TR) * KNN_STRIDE];
    float* hcs = lds;
    float* hrs = lds + KNN_TC * KNN_STRIDE;
    int tid = threadIdx.x;
    int tx = tid & 7;
    int ty = tid >> 3;
    int c0 = blockIdx.x * KNN_TC;
    int rbase = blockIdx.y * chunk;
    int rend = min(rbase + chunk, NR);

    float bv[8][3];
    int bi[8][3];
#pragma unroll
    for (int i = 0; i < 8; i++)
#pragma unroll
        for (int j = 0; j < 3; j++) { bv[i][j] = 3.4e38f; bi[i][j] = 0x7fffffff; }

    for (int rt = rbase; rt < rend; rt += KNN_TR) {
        float acc[8][4];
#pragma unroll
        for (int i = 0; i < 8; i++)
#pragma unroll
            for (int j = 0; j < 4; j++) acc[i][j] = 0.f;

        for (int ks = 0; ks < 128; ks += 32) {
            __syncthreads();
#pragma unroll
            for (int q = 0; q < 2; q++) {
                int idx = q * 256 + tid;
                int row = idx >> 3, col4 = idx & 7;
                int c = c0 + row;
                float4 v = make_float4(0.f, 0.f, 0.f, 0.f);
                if (c < NC) v = *(const float4*)&hc[(size_t)c * 128 + ks + col4 * 4];
                *(float4*)&hcs[row * KNN_STRIDE + col4 * 4] = v;
            }
#pragma unroll
            for (int q = 0; q < 4; q++) {
                int idx = q * 256 + tid;
                int row = idx >> 3, col4 = idx & 7;
                int r = rt + row;
                float4 v = make_float4(0.f, 0.f, 0.f, 0.f);
                if (r < rend) v = *(const float4*)&hr[(size_t)r * 128 + ks + col4 * 4];
                *(float4*)&hrs[row * KNN_STRIDE + col4 * 4] = v;
            }
            __syncthreads();
#pragma unroll 2
            for (int kk4 = 0; kk4 < 8; kk4++) {
                float4 b[4];
#pragma unroll
                for (int j = 0; j < 4; j++)
                    b[j] = *(const float4*)&hrs[(ty + 32 * j) * KNN_STRIDE + kk4 * 4];
#pragma unroll
                for (int i = 0; i < 8; i++) {
                    float4 a = *(const float4*)&hcs[(tx + 8 * i) * KNN_STRIDE + kk4 * 4];
#pragma unroll
                    for (int j = 0; j < 4; j++) {
                        acc[i][j] += a.x * b[j].x;
                        acc[i][j] += a.y * b[j].y;
                        acc[i][j] += a.z * b[j].z;
                        acc[i][j] += a.w * b[j].w;
                    }
                }
            }
        }
#pragma unroll
        for (int j = 0; j < 4; j++) {
            int r = rt + ty + 32 * j;
            if (r < rend) {
                float rnv = rn[r];
#pragma unroll
                for (int i = 0; i < 8; i++) {
                    float d = rnv - 2.f * acc[i][j];
                    ins3(d, r, bv[i], bi[i]);
                }
            }
        }
    }

    float* mv = lds;
    int* mi = (int*)(lds + KNN_TC * 48);
    float fv[3] = {3.4e38f, 3.4e38f, 3.4e38f};
    int fi[3] = {0x7fffffff, 0x7fffffff, 0x7fffffff};

    __syncthreads();
    if (ty < 16) {
#pragma unroll
        for (int i = 0; i < 8; i++) {
            int cc = tx + 8 * i;
#pragma unroll
            for (int j = 0; j < 3; j++) {
                mv[cc * 48 + ty * 3 + j] = bv[i][j];
                mi[cc * 48 + ty * 3 + j] = bi[i][j];
            }
        }
    }
    __syncthreads();
    if (tid < KNN_TC) {
        for (int t = 0; t < 48; t++) ins3(mv[tid * 48 + t], mi[tid * 48 + t], fv, fi);
    }
    __syncthreads();
    if (ty >= 16) {
#pragma unroll
        for (int i = 0; i < 8; i++) {
            int cc = tx + 8 * i;
#pragma unroll
            for (int j = 0; j < 3; j++) {
                mv[cc * 48 + (ty - 16) * 3 + j] = bv[i][j];
                mi[cc * 48 + (ty - 16) * 3 + j] = bi[i][j];
            }
        }
    }
    __syncthreads();
    if (tid < KNN_TC) {
        for (int t = 0; t < 48; t++) ins3(mv[tid * 48 + t], mi[tid * 48 + t], fv, fi);
        int c = c0 + tid;
        if (c < NC) {
            size_t o = ((size_t)c * KNN_NCH + blockIdx.y) * 3;
            cand_v[o + 0] = fv[0]; cand_i[o + 0] = fi[0];
            cand_v[o + 1] = fv[1]; cand_i[o + 1] = fi[1];
            cand_v[o + 2] = fv[2]; cand_i[o + 2] = fi[2];
        }
    }
}

// ---------------- fused kNN merge + pooling scatter (one block per collider) ----------------
__global__ __launch_bounds__(128) void k_mergepool(const float* __restrict__ cand_v,
                                                   const int* __restrict__ cand_i,
                                                   const float* __restrict__ hc,
                                                   float* __restrict__ psum, float* __restrict__ pcnt,
                                                   int NC, int NR) {
    int c = blockIdx.x;
    int f = threadIdx.x;
    __shared__ int kn[3];
    if (f == 0) {
        float fv[3] = {3.4e38f, 3.4e38f, 3.4e38f};
        int fi[3] = {0x7fffffff, 0x7fffffff, 0x7fffffff};
        size_t o = (size_t)c * KNN_NCH * 3;
        for (int t = 0; t < KNN_NCH * 3; t++) ins3(cand_v[o + t], cand_i[o + t], fv, fi);
#pragma unroll
        for (int j = 0; j < 3; j++) {
            kn[j] = clampi(fi[j], 0, NR - 1);
            atomicAdd(&pcnt[kn[j]], 1.f);
        }
    }
    __syncthreads();
    float v = hc[(size_t)c * 128 + f];
#pragma unroll
    for (int j = 0; j < 3; j++) atomicAdd(&psum[(size_t)kn[j] * 128 + f], v);
}

// ---------------- decode: out = [hr, pooled] @ Wd + bd ----------------
__global__ __launch_bounds__(256) void k_decode(const float* __restrict__ hr, const float* __restrict__ psum,
                                                const float* __restrict__ pcnt,
                                                const void* __restrict__ Wd,
                                                const void* __restrict__ bd,
                                                const int* __restrict__ mode_p,
                                                void* __restrict__ outv, int NR) {
    int mode = *mode_p;
    int w = (blockIdx.x * blockDim.x + threadIdx.x) >> 6;
    int lane = threadIdx.x & 63;
    if (w >= NR) return;
    float icnt = 1.f / fmaxf(pcnt[w], 1.f);
    float o0 = 0.f, o1 = 0.f, o2 = 0.f;
#pragma unroll
    for (int hh = 0; hh < 2; hh++) {
        int f = lane + hh * 64;
        float xv = hr[(size_t)w * 128 + f];
        o0 += xv * ldm(Wd, f * 3 + 0, mode);
        o1 += xv * ldm(Wd, f * 3 + 1, mode);
        o2 += xv * ldm(Wd, f * 3 + 2, mode);
        float pv = psum[(size_t)w * 128 + f] * icnt;
        o0 += pv * ldm(Wd, (128 + f) * 3 + 0, mode);
        o1 += pv * ldm(Wd, (128 + f) * 3 + 1, mode);
        o2 += pv * ldm(Wd, (128 + f) * 3 + 2, mode);
    }
#pragma unroll
    for (int d = 32; d > 0; d >>= 1) {
        o0 += __shfl_xor(o0, d, 64);
        o1 += __shfl_xor(o1, d, 64);
        o2 += __shfl_xor(o2, d, 64);
    }
    if (lane == 0) {
        float v0 = o0 + ldm(bd, 0, mode);
        float v1 = o1 + ldm(bd, 1, mode);
        float v2 = o2 + ldm(bd, 2, mode);
        if (mode) {
            float* out = (float*)outv;
            out[w * 3 + 0] = v0;
            out[w * 3 + 1] = v1;
            out[w * 3 + 2] = v2;
        } else {
            __hip_bfloat16* out = (__hip_bfloat16*)outv;
            out[w * 3 + 0] = __float2bfloat16(v0);
            out[w * 3 + 1] = __float2bfloat16(v1);
            out[w * 3 + 2] = __float2bfloat16(v2);
        }
    }
}

extern "C" void kernel_launch(void* const* d_in, const int* in_sizes, int n_in,
                              void* d_out, int out_size, void* d_ws, size_t ws_size,
                              hipStream_t stream) {
    const void* x_r = d_in[0];
    const int* ei_r = (const int*)d_in[1];
    const void* x_c = d_in[2];
    const int* ei_c = (const int*)d_in[3];
    const void* W1r = d_in[4];
    const void* as1r = d_in[5];
    const void* ad1r = d_in[6];
    const void* b1r = d_in[7];
    const void* W2r = d_in[8];
    const void* as2r = d_in[9];
    const void* ad2r = d_in[10];
    const void* b2r = d_in[11];
    const void* W1c = d_in[12];
    const void* as1c = d_in[13];
    const void* ad1c = d_in[14];
    const void* b1c = d_in[15];
    const void* W2c = d_in[16];
    const void* as2c = d_in[17];
    const void* ad2c = d_in[18];
    const void* b2c = d_in[19];
    const void* Wd = d_in[20];
    const void* bd = d_in[21];

    const int NR = in_sizes[0] / 3;
    const int ER = in_sizes[1] / 2;
    const int NC = in_sizes[2] / 6;
    const int EC = in_sizes[3] / 2;

    // ---- workspace layout: non-zeroed region first, then ONE contiguous zero region ----
    char* p = (char*)d_ws;
    size_t used = 0;
    auto alloc = [&](size_t bytes) {
        void* q = (void*)(p + used);
        used += (bytes + 255) & ~(size_t)255;
        return q;
    };
    float* r_A = (float*)alloc((size_t)NR * 128 * 4);
    float* r_B = (float*)alloc((size_t)NR * 128 * 4);
    float* c_A = (float*)alloc((size_t)NC * 128 * 4);  // later cand_v/cand_i alias
    float* c_B = (float*)alloc((size_t)NC * 128 * 4);
    float* r_as = (float*)alloc((size_t)NR * 4);
    float* r_ad = (float*)alloc((size_t)NR * 4);
    float* c_as = (float*)alloc((size_t)NC * 4);
    float* c_ad = (float*)alloc((size_t)NC * 4);
    float* rn = (float*)alloc((size_t)NR * 4);         // own buffer: r_as stays live in agg2
    int* r_off = (int*)alloc((size_t)(NR + 1) * 4);
    int* r_sorted = (int*)alloc((size_t)ER * 4);
    int* c_off = (int*)alloc((size_t)(NC + 1) * 4);
    int* c_sorted = (int*)alloc((size_t)EC * 4);
    // zero region (single memset covers all of these, padding included)
    size_t zero_off = used;
    float* psum = (float*)alloc((size_t)NR * 128 * 4);
    float* pcnt = (float*)alloc((size_t)NR * 4);
    int* r_deg = (int*)alloc((size_t)NR * 4);
    int* r_cur = (int*)alloc((size_t)NR * 4);
    int* c_deg = (int*)alloc((size_t)NC * 4);
    int* c_cur = (int*)alloc((size_t)NC * 4);
    int* mode_p = (int*)alloc(256);
    size_t zero_len = used - zero_off;

    // aliases (c_A dead after collider agg2)
    float* cand_v = c_A;
    int* cand_i = (int*)(c_A + (size_t)NC * KNN_NCH * 3);

    if (ws_size < used) return;  // tripwire

    (void)hipMemsetAsync(p + zero_off, 0, zero_len, stream);

    // ---- dtype detect (both tensors, one launch) ----
    k_detect2<<<(in_sizes[0] + in_sizes[2] + 255) / 256, 256, 0, stream>>>(
        (const unsigned short*)x_r, in_sizes[0], (const unsigned short*)x_c, in_sizes[2], mode_p);

    // ---- fused edge sort (both graphs) ----
    k_hist2<<<(ER + EC + 255) / 256, 256, 0, stream>>>(ei_r + ER, ER, r_deg, NR, ei_c + EC, EC, c_deg, NC);
    k_scan2<<<2, 1024, 0, stream>>>(r_deg, r_off, NR, c_deg, c_off, NC);
    k_scatter2<<<(ER + EC + 255) / 256, 256, 0, stream>>>(ei_r, ei_r + ER, ER, r_off, r_cur, r_sorted, NR,
                                                          ei_c, ei_c + EC, EC, c_off, c_cur, c_sorted, NC);

    const int aggBlocksR = (NR * 64 + 255) / 256;
    const int aggBlocksC = (NC * 64 + 255) / 256;

    // ---- GAT layer 1 (both branches fused): lin -> A, agg -> B ----
    k_lin1_both<<<NR + NC, 128, 0, stream>>>(x_r, W1r, as1r, ad1r, r_A, r_as, r_ad, NR,
                                             x_c, W1c, as1c, ad1c, c_A, c_as, c_ad, NC, mode_p);
    k_agg_both<<<aggBlocksR + aggBlocksC, 256, 0, stream>>>(
        r_A, r_as, r_ad, r_off, r_sorted, b1r, r_B, NR,
        c_A, c_as, c_ad, c_off, c_sorted, b1c, c_B, NC, mode_p, aggBlocksR, rn, 0);

    // ---- GAT layer 2 (both branches fused): lin(B) -> A, agg -> B; resting agg also writes rn ----
    k_lin2_both<<<NR + NC, 128, 0, stream>>>(r_B, W2r, as2r, ad2r, r_A, r_as, r_ad, NR,
                                             c_B, W2c, as2c, ad2c, c_A, c_as, c_ad, NC, mode_p);
    k_agg_both<<<aggBlocksR + aggBlocksC, 256, 0, stream>>>(
        r_A, r_as, r_ad, r_off, r_sorted, b2r, r_B, NR,
        c_A, c_as, c_ad, c_off, c_sorted, b2c, c_B, NC, mode_p, aggBlocksR, rn, 1);

    // ---- kNN + fused merge/pool ----
    int chunk = (NR + KNN_NCH - 1) / KNN_NCH;
    dim3 kg((NC + KNN_TC - 1) / KNN_TC, KNN_NCH);
    k_knn_part<<<kg, 256, 0, stream>>>(r_B, c_B, rn, cand_v, cand_i, NR, NC, chunk);
    k_mergepool<<<NC, 128, 0, stream>>>(cand_v, cand_i, c_B, psum, pcnt, NC, NR);

    // ---- decode ----
    k_decode<<<aggBlocksR, 256, 0, stream>>>(r_B, psum, pcnt, Wd, bd, mode_p, d_out, NR);
}

// Round 12
// 790.252 us; speedup vs baseline: 1.2020x; 1.0169x over previous
//
#include <hip/hip_runtime.h>
#include <hip/hip_bf16.h>
#include <cstdint>
#include <cstddef>

#define DI __device__ __forceinline__

DI float lrelu(float x) { return x > 0.f ? x : 0.2f * x; }
DI int clampi(int v, int lo, int hi) { return v < lo ? lo : (v > hi ? hi : v); }
DI float clampf(float v) { return fminf(fmaxf(v, -1e15f), 1e15f); }

// dual-mode load of a "float tensor": mode 0 = bf16 storage, mode 1 = fp32 storage
DI float ldm(const void* p, int i, int mode) {
    if (mode) return ((const float*)p)[i];
    return __bfloat162float(((const __hip_bfloat16*)p)[i]);
}

// better-than comparator: smaller value wins; tie -> smaller index (matches top_k)
DI void ins3(float v, int ix, float bv[3], int bi[3]) {
    bool b2 = (v < bv[2]) || (v == bv[2] && ix < bi[2]);
    if (!b2) return;
    bool b0 = (v < bv[0]) || (v == bv[0] && ix < bi[0]);
    bool b1 = (v < bv[1]) || (v == bv[1] && ix < bi[1]);
    if (b0) {
        bv[2] = bv[1]; bi[2] = bi[1];
        bv[1] = bv[0]; bi[1] = bi[0];
        bv[0] = v;     bi[0] = ix;
    } else if (b1) {
        bv[2] = bv[1]; bi[2] = bi[1];
        bv[1] = v;     bi[1] = ix;
    } else {
        bv[2] = v;     bi[2] = ix;
    }
}

// ---------------- fused hist (both graphs) + dtype detect ----------------
__global__ void k_pre(const int* __restrict__ dstR, int ER, int* __restrict__ degR, int NR,
                      const int* __restrict__ dstC, int EC, int* __restrict__ degC, int NC,
                      const unsigned short* __restrict__ u0, int n0,
                      const unsigned short* __restrict__ u1, int n1,
                      int* __restrict__ flag, int histBlocks) {
    int bid = blockIdx.x;
    if (bid < histBlocks) {
        int e = bid * 256 + threadIdx.x;
        if (e < ER) {
            unsigned d = (unsigned)dstR[e];
            if (d < (unsigned)NR) atomicAdd(&degR[d], 1);
        } else if (e < ER + EC) {
            unsigned d = (unsigned)dstC[e - ER];
            if (d < (unsigned)NC) atomicAdd(&degC[d], 1);
        }
    } else {
        int i = (bid - histBlocks) * 256 + threadIdx.x;
        if (i < n0 + n1) {
            unsigned short v = (i < n0) ? u0[i] : u1[i - n0];
            if (((v >> 7) & 0xFF) == 0xFF) atomicOr(flag, 1);
        }
    }
}

// ---------------- low-barrier scan: thread-serial spans + one 1024-wide block scan ----------------
// Replaces the chunked Hillis-Steele (10 chunks x ~22 barriers at 2 blocks on 256 CUs).
__global__ __launch_bounds__(1024) void k_scan2(const int* __restrict__ degR, int* __restrict__ offR, int NR,
                                                const int* __restrict__ degC, int* __restrict__ offC, int NC) {
    const int* deg = blockIdx.x ? degC : degR;
    int* off = blockIdx.x ? offC : offR;
    int N = blockIdx.x ? NC : NR;
    __shared__ int s[1024];
    int t = threadIdx.x;
    int span = (N + 1023) >> 10;
    int lo = t * span;
    int hi = min(lo + span, N);
    int sum = 0;
    for (int i = lo; i < hi; i++) sum += deg[i];
    s[t] = sum;
    __syncthreads();
    for (int d = 1; d < 1024; d <<= 1) {
        int v = (t >= d) ? s[t - d] : 0;
        __syncthreads();
        s[t] += v;
        __syncthreads();
    }
    int run = s[t] - sum;  // exclusive prefix of this thread's span
    for (int i = lo; i < hi; i++) { off[i] = run; run += deg[i]; }
    if (t == 1023) off[N] = s[1023];
}

// ---------------- fused scatter (both graphs) + layer-1 linear (both branches) ----------------
__global__ __launch_bounds__(128) void k_scatlin(
    // lin1 args
    const void* __restrict__ xR, const void* __restrict__ WR,
    const void* __restrict__ avsR, const void* __restrict__ avdR,
    float* __restrict__ hR, float* __restrict__ asR, float* __restrict__ adR, int NR,
    const void* __restrict__ xC, const void* __restrict__ WC,
    const void* __restrict__ avsC, const void* __restrict__ avdC,
    float* __restrict__ hC, float* __restrict__ asC, float* __restrict__ adC, int NC,
    const int* __restrict__ mode_p,
    // scatter args
    const int* __restrict__ srcR, const int* __restrict__ dstR, int ER,
    const int* __restrict__ offR, int* __restrict__ curR, int* __restrict__ sortedR,
    const int* __restrict__ srcC, const int* __restrict__ dstC, int EC,
    const int* __restrict__ offC, int* __restrict__ curC, int* __restrict__ sortedC) {
    int bid = blockIdx.x;
    if (bid < NR + NC) {
        // ---- lin1 body (identical math to round 11) ----
        int mode = *mode_p;
        int f = threadIdx.x;
        const void *x, *W, *avs, *avd;
        float *h, *as_, *ad_;
        int n, fin;
        if (bid < NR) { n = bid; fin = 3; x = xR; W = WR; avs = avsR; avd = avdR; h = hR; as_ = asR; ad_ = adR; }
        else          { n = bid - NR; fin = 6; x = xC; W = WC; avs = avsC; avd = avdC; h = hC; as_ = asC; ad_ = adC; }
        __shared__ float xs[8];
        __shared__ float r1[128], r2[128];
        if (f < fin) xs[f] = ldm(x, n * fin + f, mode);
        __syncthreads();
        float acc = 0.f;
        for (int k = 0; k < fin; k++) acc += xs[k] * ldm(W, k * 128 + f, mode);
        acc = clampf(acc);
        h[(size_t)n * 128 + f] = acc;
        r1[f] = acc * ldm(avs, f, mode);
        r2[f] = acc * ldm(avd, f, mode);
        __syncthreads();
        for (int s2 = 64; s2 > 0; s2 >>= 1) {
            if (f < s2) { r1[f] += r1[f + s2]; r2[f] += r2[f + s2]; }
            __syncthreads();
        }
        if (f == 0) { as_[n] = clampf(r1[0]); ad_[n] = clampf(r2[0]); }
    } else {
        // ---- scatter body ----
        int e = (bid - (NR + NC)) * 128 + threadIdx.x;
        if (e < ER) {
            unsigned d = (unsigned)dstR[e];
            if (d < (unsigned)NR) {
                int p = offR[d] + atomicAdd(&curR[d], 1);
                sortedR[p] = clampi(srcR[e], 0, NR - 1);
            }
        } else if (e < ER + EC) {
            int e2 = e - ER;
            unsigned d = (unsigned)dstC[e2];
            if (d < (unsigned)NC) {
                int p = offC[d] + atomicAdd(&curC[d], 1);
                sortedC[p] = clampi(srcC[e2], 0, NC - 1);
            }
        }
    }
}

// ---------------- fused layer-2 linear (both branches, fp32 input) ----------------
__global__ __launch_bounds__(128) void k_lin2_both(
    const float* __restrict__ xR, const void* __restrict__ WR,
    const void* __restrict__ avsR, const void* __restrict__ avdR,
    float* __restrict__ hR, float* __restrict__ asR, float* __restrict__ adR, int NR,
    const float* __restrict__ xC, const void* __restrict__ WC,
    const void* __restrict__ avsC, const void* __restrict__ avdC,
    float* __restrict__ hC, float* __restrict__ asC, float* __restrict__ adC, int NC,
    const int* __restrict__ mode_p) {
    int mode = *mode_p;
    int bid = blockIdx.x;
    int f = threadIdx.x;
    const float* x;
    const void *W, *avs, *avd;
    float *h, *as_, *ad_;
    int n;
    if (bid < NR) { n = bid; x = xR; W = WR; avs = avsR; avd = avdR; h = hR; as_ = asR; ad_ = adR; }
    else          { n = bid - NR; x = xC; W = WC; avs = avsC; avd = avdC; h = hC; as_ = asC; ad_ = adC; }
    __shared__ float xs[128];
    __shared__ float r1[128], r2[128];
    xs[f] = x[(size_t)n * 128 + f];
    __syncthreads();
    float acc = 0.f;
#pragma unroll
    for (int k = 0; k < 128; k++) acc += xs[k] * ldm(W, k * 128 + f, mode);
    acc = clampf(acc);
    h[(size_t)n * 128 + f] = acc;
    r1[f] = acc * ldm(avs, f, mode);
    r2[f] = acc * ldm(avd, f, mode);
    __syncthreads();
    for (int s2 = 64; s2 > 0; s2 >>= 1) {
        if (f < s2) { r1[f] += r1[f + s2]; r2[f] += r2[f + s2]; }
        __syncthreads();
    }
    if (f == 0) { as_[n] = clampf(r1[0]); ad_[n] = clampf(r2[0]); }
}

// ---------------- fused softmax-aggregate (both branches; optional rn epilogue) ----------------
__global__ __launch_bounds__(256) void k_agg_both(
    const float* __restrict__ hR, const float* __restrict__ asR, const float* __restrict__ adR,
    const int* __restrict__ offR, const int* __restrict__ srtR, const void* __restrict__ biasR,
    float* __restrict__ outR, int NR,
    const float* __restrict__ hC, const float* __restrict__ asC, const float* __restrict__ adC,
    const int* __restrict__ offC, const int* __restrict__ srtC, const void* __restrict__ biasC,
    float* __restrict__ outC, int NC,
    const int* __restrict__ mode_p, int blocksR, float* __restrict__ rn, int do_rn) {
    int mode = *mode_p;
    int bid = blockIdx.x;
    int wid = threadIdx.x >> 6;
    int lane = threadIdx.x & 63;
    const float *h, *as_, *ad_;
    const int *off, *sorted;
    const void* bias;
    float* out;
    int w, N, isR;
    if (bid < blocksR) { isR = 1; w = bid * 4 + wid; N = NR; h = hR; as_ = asR; ad_ = adR; off = offR; sorted = srtR; bias = biasR; out = outR; }
    else               { isR = 0; w = (bid - blocksR) * 4 + wid; N = NC; h = hC; as_ = asC; ad_ = adC; off = offC; sorted = srtC; bias = biasC; out = outC; }
    if (w >= N) return;
    int s0 = off[w], s1 = off[w + 1];
    float adv = ad_[w];
    float eself = lrelu(as_[w] + adv);
    float m = eself;
    for (int j = s0 + lane; j < s1; j += 64) {
        int s = clampi(sorted[j], 0, N - 1);
        m = fmaxf(m, lrelu(as_[s] + adv));
    }
#pragma unroll
    for (int d = 32; d > 0; d >>= 1) m = fmaxf(m, __shfl_xor(m, d, 64));
    const float2* h2 = (const float2*)h;
    float wself = __expf(eself - m);
    float denom = wself;
    float2 hv = h2[(size_t)w * 64 + lane];
    float a0 = wself * hv.x, a1 = wself * hv.y;
    for (int j = s0; j < s1; j++) {
        int s = clampi(sorted[j], 0, N - 1);
        float wj = __expf(lrelu(as_[s] + adv) - m);
        denom += wj;
        float2 hs = h2[(size_t)s * 64 + lane];
        a0 += wj * hs.x;
        a1 += wj * hs.y;
    }
    float inv = 1.f / fmaxf(denom, 1e-30f);
    float o0 = fminf(fmaxf(a0 * inv + ldm(bias, lane * 2, mode), 0.f), 1e15f);
    float o1 = fminf(fmaxf(a1 * inv + ldm(bias, lane * 2 + 1, mode), 0.f), 1e15f);
    out[(size_t)w * 128 + lane * 2] = o0;
    out[(size_t)w * 128 + lane * 2 + 1] = o1;
    if (do_rn && isR) {
        float s = o0 * o0 + o1 * o1;
#pragma unroll
        for (int d = 32; d > 0; d >>= 1) s += __shfl_xor(s, d, 64);
        if (lane == 0) rn[w] = s;
    }
}

// ---------------- kNN partial (UNCHANGED: 8x4 @256thr, unroll 2; round 10/11 verified) ----------------
#define KNN_TC 64
#define KNN_TR 128
#define KNN_NCH 16
#define KNN_STRIDE 36

__global__ __launch_bounds__(256)
void k_knn_part(const float* __restrict__ hr,
                const float* __restrict__ hc,
                const float* __restrict__ rn,
                float* __restrict__ cand_v, int* __restrict__ cand_i,
                int NR, int NC, int chunk) {
    __shared__ float lds[(KNN_TC + KNN_TR) * KNN_STRIDE];
    float* hcs = lds;
    float* hrs = lds + KNN_TC * KNN_STRIDE;
    int tid = threadIdx.x;
    int tx = tid & 7;
    int ty = tid >> 3;
    int c0 = blockIdx.x * KNN_TC;
    int rbase = blockIdx.y * chunk;
    int rend = min(rbase + chunk, NR);

    float bv[8][3];
    int bi[8][3];
#pragma unroll
    for (int i = 0; i < 8; i++)
#pragma unroll
        for (int j = 0; j < 3; j++) { bv[i][j] = 3.4e38f; bi[i][j] = 0x7fffffff; }

    for (int rt = rbase; rt < rend; rt += KNN_TR) {
        float acc[8][4];
#pragma unroll
        for (int i = 0; i < 8; i++)
#pragma unroll
            for (int j = 0; j < 4; j++) acc[i][j] = 0.f;

        for (int ks = 0; ks < 128; ks += 32) {
            __syncthreads();
#pragma unroll
            for (int q = 0; q < 2; q++) {
                int idx = q * 256 + tid;
                int row = idx >> 3, col4 = idx & 7;
                int c = c0 + row;
                float4 v = make_float4(0.f, 0.f, 0.f, 0.f);
                if (c < NC) v = *(const float4*)&hc[(size_t)c * 128 + ks + col4 * 4];
                *(float4*)&hcs[row * KNN_STRIDE + col4 * 4] = v;
            }
#pragma unroll
            for (int q = 0; q < 4; q++) {
                int idx = q * 256 + tid;
                int row = idx >> 3, col4 = idx & 7;
                int r = rt + row;
                float4 v = make_float4(0.f, 0.f, 0.f, 0.f);
                if (r < rend) v = *(const float4*)&hr[(size_t)r * 128 + ks + col4 * 4];
                *(float4*)&hrs[row * KNN_STRIDE + col4 * 4] = v;
            }
            __syncthreads();
#pragma unroll 2
            for (int kk4 = 0; kk4 < 8; kk4++) {
                float4 b[4];
#pragma unroll
                for (int j = 0; j < 4; j++)
                    b[j] = *(const float4*)&hrs[(ty + 32 * j) * KNN_STRIDE + kk4 * 4];
#pragma unroll
                for (int i = 0; i < 8; i++) {
                    float4 a = *(const float4*)&hcs[(tx + 8 * i) * KNN_STRIDE + kk4 * 4];
#pragma unroll
                    for (int j = 0; j < 4; j++) {
                        acc[i][j] += a.x * b[j].x;
                        acc[i][j] += a.y * b[j].y;
                        acc[i][j] += a.z * b[j].z;
                        acc[i][j] += a.w * b[j].w;
                    }
                }
            }
        }
#pragma unroll
        for (int j = 0; j < 4; j++) {
            int r = rt + ty + 32 * j;
            if (r < rend) {
                float rnv = rn[r];
#pragma unroll
                for (int i = 0; i < 8; i++) {
                    float d = rnv - 2.f * acc[i][j];
                    ins3(d, r, bv[i], bi[i]);
                }
            }
        }
    }

    float* mv = lds;
    int* mi = (int*)(lds + KNN_TC * 48);
    float fv[3] = {3.4e38f, 3.4e38f, 3.4e38f};
    int fi[3] = {0x7fffffff, 0x7fffffff, 0x7fffffff};

    __syncthreads();
    if (ty < 16) {
#pragma unroll
        for (int i = 0; i < 8; i++) {
            int cc = tx + 8 * i;
#pragma unroll
            for (int j = 0; j < 3; j++) {
                mv[cc * 48 + ty * 3 + j] = bv[i][j];
                mi[cc * 48 + ty * 3 + j] = bi[i][j];
            }
        }
    }
    __syncthreads();
    if (tid < KNN_TC) {
        for (int t = 0; t < 48; t++) ins3(mv[tid * 48 + t], mi[tid * 48 + t], fv, fi);
    }
    __syncthreads();
    if (ty >= 16) {
#pragma unroll
        for (int i = 0; i < 8; i++) {
            int cc = tx + 8 * i;
#pragma unroll
            for (int j = 0; j < 3; j++) {
                mv[cc * 48 + (ty - 16) * 3 + j] = bv[i][j];
                mi[cc * 48 + (ty - 16) * 3 + j] = bi[i][j];
            }
        }
    }
    __syncthreads();
    if (tid < KNN_TC) {
        for (int t = 0; t < 48; t++) ins3(mv[tid * 48 + t], mi[tid * 48 + t], fv, fi);
        int c = c0 + tid;
        if (c < NC) {
            size_t o = ((size_t)c * KNN_NCH + blockIdx.y) * 3;
            cand_v[o + 0] = fv[0]; cand_i[o + 0] = fi[0];
            cand_v[o + 1] = fv[1]; cand_i[o + 1] = fi[1];
            cand_v[o + 2] = fv[2]; cand_i[o + 2] = fi[2];
        }
    }
}

// ---------------- fused kNN merge + pooling scatter (one block per collider) ----------------
__global__ __launch_bounds__(128) void k_mergepool(const float* __restrict__ cand_v,
                                                   const int* __restrict__ cand_i,
                                                   const float* __restrict__ hc,
                                                   float* __restrict__ psum, float* __restrict__ pcnt,
                                                   int NC, int NR) {
    int c = blockIdx.x;
    int f = threadIdx.x;
    __shared__ int kn[3];
    if (f == 0) {
        float fv[3] = {3.4e38f, 3.4e38f, 3.4e38f};
        int fi[3] = {0x7fffffff, 0x7fffffff, 0x7fffffff};
        size_t o = (size_t)c * KNN_NCH * 3;
        for (int t = 0; t < KNN_NCH * 3; t++) ins3(cand_v[o + t], cand_i[o + t], fv, fi);
#pragma unroll
        for (int j = 0; j < 3; j++) {
            kn[j] = clampi(fi[j], 0, NR - 1);
            atomicAdd(&pcnt[kn[j]], 1.f);
        }
    }
    __syncthreads();
    float v = hc[(size_t)c * 128 + f];
#pragma unroll
    for (int j = 0; j < 3; j++) atomicAdd(&psum[(size_t)kn[j] * 128 + f], v);
}

// ---------------- decode: out = [hr, pooled] @ Wd + bd ----------------
__global__ __launch_bounds__(256) void k_decode(const float* __restrict__ hr, const float* __restrict__ psum,
                                                const float* __restrict__ pcnt,
                                                const void* __restrict__ Wd,
                                                const void* __restrict__ bd,
                                                const int* __restrict__ mode_p,
                                                void* __restrict__ outv, int NR) {
    int mode = *mode_p;
    int w = (blockIdx.x * blockDim.x + threadIdx.x) >> 6;
    int lane = threadIdx.x & 63;
    if (w >= NR) return;
    float icnt = 1.f / fmaxf(pcnt[w], 1.f);
    float o0 = 0.f, o1 = 0.f, o2 = 0.f;
#pragma unroll
    for (int hh = 0; hh < 2; hh++) {
        int f = lane + hh * 64;
        float xv = hr[(size_t)w * 128 + f];
        o0 += xv * ldm(Wd, f * 3 + 0, mode);
        o1 += xv * ldm(Wd, f * 3 + 1, mode);
        o2 += xv * ldm(Wd, f * 3 + 2, mode);
        float pv = psum[(size_t)w * 128 + f] * icnt;
        o0 += pv * ldm(Wd, (128 + f) * 3 + 0, mode);
        o1 += pv * ldm(Wd, (128 + f) * 3 + 1, mode);
        o2 += pv * ldm(Wd, (128 + f) * 3 + 2, mode);
    }
#pragma unroll
    for (int d = 32; d > 0; d >>= 1) {
        o0 += __shfl_xor(o0, d, 64);
        o1 += __shfl_xor(o1, d, 64);
        o2 += __shfl_xor(o2, d, 64);
    }
    if (lane == 0) {
        float v0 = o0 + ldm(bd, 0, mode);
        float v1 = o1 + ldm(bd, 1, mode);
        float v2 = o2 + ldm(bd, 2, mode);
        if (mode) {
            float* out = (float*)outv;
            out[w * 3 + 0] = v0;
            out[w * 3 + 1] = v1;
            out[w * 3 + 2] = v2;
        } else {
            __hip_bfloat16* out = (__hip_bfloat16*)outv;
            out[w * 3 + 0] = __float2bfloat16(v0);
            out[w * 3 + 1] = __float2bfloat16(v1);
            out[w * 3 + 2] = __float2bfloat16(v2);
        }
    }
}

extern "C" void kernel_launch(void* const* d_in, const int* in_sizes, int n_in,
                              void* d_out, int out_size, void* d_ws, size_t ws_size,
                              hipStream_t stream) {
    const void* x_r = d_in[0];
    const int* ei_r = (const int*)d_in[1];
    const void* x_c = d_in[2];
    const int* ei_c = (const int*)d_in[3];
    const void* W1r = d_in[4];
    const void* as1r = d_in[5];
    const void* ad1r = d_in[6];
    const void* b1r = d_in[7];
    const void* W2r = d_in[8];
    const void* as2r = d_in[9];
    const void* ad2r = d_in[10];
    const void* b2r = d_in[11];
    const void* W1c = d_in[12];
    const void* as1c = d_in[13];
    const void* ad1c = d_in[14];
    const void* b1c = d_in[15];
    const void* W2c = d_in[16];
    const void* as2c = d_in[17];
    const void* ad2c = d_in[18];
    const void* b2c = d_in[19];
    const void* Wd = d_in[20];
    const void* bd = d_in[21];

    const int NR = in_sizes[0] / 3;
    const int ER = in_sizes[1] / 2;
    const int NC = in_sizes[2] / 6;
    const int EC = in_sizes[3] / 2;

    // ---- workspace layout: non-zeroed region first, then ONE contiguous zero region ----
    char* p = (char*)d_ws;
    size_t used = 0;
    auto alloc = [&](size_t bytes) {
        void* q = (void*)(p + used);
        used += (bytes + 255) & ~(size_t)255;
        return q;
    };
    float* r_A = (float*)alloc((size_t)NR * 128 * 4);
    float* r_B = (float*)alloc((size_t)NR * 128 * 4);
    float* c_A = (float*)alloc((size_t)NC * 128 * 4);  // later cand_v/cand_i alias
    float* c_B = (float*)alloc((size_t)NC * 128 * 4);
    float* r_as = (float*)alloc((size_t)NR * 4);
    float* r_ad = (float*)alloc((size_t)NR * 4);
    float* c_as = (float*)alloc((size_t)NC * 4);
    float* c_ad = (float*)alloc((size_t)NC * 4);
    float* rn = (float*)alloc((size_t)NR * 4);
    int* r_off = (int*)alloc((size_t)(NR + 1) * 4);
    int* r_sorted = (int*)alloc((size_t)ER * 4);
    int* c_off = (int*)alloc((size_t)(NC + 1) * 4);
    int* c_sorted = (int*)alloc((size_t)EC * 4);
    // zero region (single memset covers all of these, padding included)
    size_t zero_off = used;
    float* psum = (float*)alloc((size_t)NR * 128 * 4);
    float* pcnt = (float*)alloc((size_t)NR * 4);
    int* r_deg = (int*)alloc((size_t)NR * 4);
    int* r_cur = (int*)alloc((size_t)NR * 4);
    int* c_deg = (int*)alloc((size_t)NC * 4);
    int* c_cur = (int*)alloc((size_t)NC * 4);
    int* mode_p = (int*)alloc(256);
    size_t zero_len = used - zero_off;

    // aliases (c_A dead after collider agg2)
    float* cand_v = c_A;
    int* cand_i = (int*)(c_A + (size_t)NC * KNN_NCH * 3);

    if (ws_size < used) return;  // tripwire

    (void)hipMemsetAsync(p + zero_off, 0, zero_len, stream);

    // ---- fused hist (both graphs) + dtype detect ----
    int histBlocks = (ER + EC + 255) / 256;
    int detBlocks = (in_sizes[0] + in_sizes[2] + 255) / 256;
    k_pre<<<histBlocks + detBlocks, 256, 0, stream>>>(
        ei_r + ER, ER, r_deg, NR, ei_c + EC, EC, c_deg, NC,
        (const unsigned short*)x_r, in_sizes[0], (const unsigned short*)x_c, in_sizes[2],
        mode_p, histBlocks);

    // ---- low-barrier scan (both graphs, 2 blocks) ----
    k_scan2<<<2, 1024, 0, stream>>>(r_deg, r_off, NR, c_deg, c_off, NC);

    // ---- fused scatter (both graphs) + layer-1 linear (both branches) ----
    int scatBlocks = (ER + EC + 127) / 128;
    k_scatlin<<<NR + NC + scatBlocks, 128, 0, stream>>>(
        x_r, W1r, as1r, ad1r, r_A, r_as, r_ad, NR,
        x_c, W1c, as1c, ad1c, c_A, c_as, c_ad, NC, mode_p,
        ei_r, ei_r + ER, ER, r_off, r_cur, r_sorted,
        ei_c, ei_c + EC, EC, c_off, c_cur, c_sorted);

    const int aggBlocksR = (NR * 64 + 255) / 256;
    const int aggBlocksC = (NC * 64 + 255) / 256;

    // ---- GAT layer 1 aggregate (both branches) ----
    k_agg_both<<<aggBlocksR + aggBlocksC, 256, 0, stream>>>(
        r_A, r_as, r_ad, r_off, r_sorted, b1r, r_B, NR,
        c_A, c_as, c_ad, c_off, c_sorted, b1c, c_B, NC, mode_p, aggBlocksR, rn, 0);

    // ---- GAT layer 2 (both branches): lin(B) -> A, agg -> B; resting agg also writes rn ----
    k_lin2_both<<<NR + NC, 128, 0, stream>>>(r_B, W2r, as2r, ad2r, r_A, r_as, r_ad, NR,
                                             c_B, W2c, as2c, ad2c, c_A, c_as, c_ad, NC, mode_p);
    k_agg_both<<<aggBlocksR + aggBlocksC, 256, 0, stream>>>(
        r_A, r_as, r_ad, r_off, r_sorted, b2r, r_B, NR,
        c_A, c_as, c_ad, c_off, c_sorted, b2c, c_B, NC, mode_p, aggBlocksR, rn, 1);

    // ---- kNN + fused merge/pool ----
    int chunk = (NR + KNN_NCH - 1) / KNN_NCH;
    dim3 kg((NC + KNN_TC - 1) / KNN_TC, KNN_NCH);
    k_knn_part<<<kg, 256, 0, stream>>>(r_B, c_B, rn, cand_v, cand_i, NR, NC, chunk);
    k_mergepool<<<NC, 128, 0, stream>>>(cand_v, cand_i, c_B, psum, pcnt, NC, NR);

    // ---- decode ----
    k_decode<<<aggBlocksR, 256, 0, stream>>>(r_B, psum, pcnt, Wd, bd, mode_p, d_out, NR);
}

// Round 13
// 734.942 us; speedup vs baseline: 1.2924x; 1.0753x over previous
//
#include <hip/hip_runtime.h>
#include <hip/hip_bf16.h>
#include <cstdint>
#include <cstddef>

#define DI __device__ __forceinline__

DI float lrelu(float x) { return x > 0.f ? x : 0.2f * x; }
DI int clampi(int v, int lo, int hi) { return v < lo ? lo : (v > hi ? hi : v); }
DI float clampf(float v) { return fminf(fmaxf(v, -1e15f), 1e15f); }

// dual-mode load of a "float tensor": mode 0 = bf16 storage, mode 1 = fp32 storage
DI float ldm(const void* p, int i, int mode) {
    if (mode) return ((const float*)p)[i];
    return __bfloat162float(((const __hip_bfloat16*)p)[i]);
}

// better-than comparator: smaller value wins; tie -> smaller index (matches top_k)
DI void ins3(float v, int ix, float bv[3], int bi[3]) {
    bool b2 = (v < bv[2]) || (v == bv[2] && ix < bi[2]);
    if (!b2) return;
    bool b0 = (v < bv[0]) || (v == bv[0] && ix < bi[0]);
    bool b1 = (v < bv[1]) || (v == bv[1] && ix < bi[1]);
    if (b0) {
        bv[2] = bv[1]; bi[2] = bi[1];
        bv[1] = bv[0]; bi[1] = bi[0];
        bv[0] = v;     bi[0] = ix;
    } else if (b1) {
        bv[2] = bv[1]; bi[2] = bi[1];
        bv[1] = v;     bi[1] = ix;
    } else {
        bv[2] = v;     bi[2] = ix;
    }
}

// ---------------- fused hist (both graphs) + dtype detect ----------------
__global__ void k_pre(const int* __restrict__ dstR, int ER, int* __restrict__ degR, int NR,
                      const int* __restrict__ dstC, int EC, int* __restrict__ degC, int NC,
                      const unsigned short* __restrict__ u0, int n0,
                      const unsigned short* __restrict__ u1, int n1,
                      int* __restrict__ flag, int histBlocks) {
    int bid = blockIdx.x;
    if (bid < histBlocks) {
        int e = bid * 256 + threadIdx.x;
        if (e < ER) {
            unsigned d = (unsigned)dstR[e];
            if (d < (unsigned)NR) atomicAdd(&degR[d], 1);
        } else if (e < ER + EC) {
            unsigned d = (unsigned)dstC[e - ER];
            if (d < (unsigned)NC) atomicAdd(&degC[d], 1);
        }
    } else {
        int i = (bid - histBlocks) * 256 + threadIdx.x;
        if (i < n0 + n1) {
            unsigned short v = (i < n0) ? u0[i] : u1[i - n0];
            if (((v >> 7) & 0xFF) == 0xFF) atomicOr(flag, 1);
        }
    }
}

// ---------------- low-barrier scan: thread-serial spans + one 1024-wide block scan ----------------
__global__ __launch_bounds__(1024) void k_scan2(const int* __restrict__ degR, int* __restrict__ offR, int NR,
                                                const int* __restrict__ degC, int* __restrict__ offC, int NC) {
    const int* deg = blockIdx.x ? degC : degR;
    int* off = blockIdx.x ? offC : offR;
    int N = blockIdx.x ? NC : NR;
    __shared__ int s[1024];
    int t = threadIdx.x;
    int span = (N + 1023) >> 10;
    int lo = t * span;
    int hi = min(lo + span, N);
    int sum = 0;
    for (int i = lo; i < hi; i++) sum += deg[i];
    s[t] = sum;
    __syncthreads();
    for (int d = 1; d < 1024; d <<= 1) {
        int v = (t >= d) ? s[t - d] : 0;
        __syncthreads();
        s[t] += v;
        __syncthreads();
    }
    int run = s[t] - sum;
    for (int i = lo; i < hi; i++) { off[i] = run; run += deg[i]; }
    if (t == 1023) off[N] = s[1023];
}

// ---------------- fused scatter (both graphs) + layer-1 linear (both branches) ----------------
__global__ __launch_bounds__(128) void k_scatlin(
    const void* __restrict__ xR, const void* __restrict__ WR,
    const void* __restrict__ avsR, const void* __restrict__ avdR,
    float* __restrict__ hR, float* __restrict__ asR, float* __restrict__ adR, int NR,
    const void* __restrict__ xC, const void* __restrict__ WC,
    const void* __restrict__ avsC, const void* __restrict__ avdC,
    float* __restrict__ hC, float* __restrict__ asC, float* __restrict__ adC, int NC,
    const int* __restrict__ mode_p,
    const int* __restrict__ srcR, const int* __restrict__ dstR, int ER,
    const int* __restrict__ offR, int* __restrict__ curR, int* __restrict__ sortedR,
    const int* __restrict__ srcC, const int* __restrict__ dstC, int EC,
    const int* __restrict__ offC, int* __restrict__ curC, int* __restrict__ sortedC) {
    int bid = blockIdx.x;
    if (bid < NR + NC) {
        int mode = *mode_p;
        int f = threadIdx.x;
        const void *x, *W, *avs, *avd;
        float *h, *as_, *ad_;
        int n, fin;
        if (bid < NR) { n = bid; fin = 3; x = xR; W = WR; avs = avsR; avd = avdR; h = hR; as_ = asR; ad_ = adR; }
        else          { n = bid - NR; fin = 6; x = xC; W = WC; avs = avsC; avd = avdC; h = hC; as_ = asC; ad_ = adC; }
        __shared__ float xs[8];
        __shared__ float r1[128], r2[128];
        if (f < fin) xs[f] = ldm(x, n * fin + f, mode);
        __syncthreads();
        float acc = 0.f;
        for (int k = 0; k < fin; k++) acc += xs[k] * ldm(W, k * 128 + f, mode);
        acc = clampf(acc);
        h[(size_t)n * 128 + f] = acc;
        r1[f] = acc * ldm(avs, f, mode);
        r2[f] = acc * ldm(avd, f, mode);
        __syncthreads();
        for (int s2 = 64; s2 > 0; s2 >>= 1) {
            if (f < s2) { r1[f] += r1[f + s2]; r2[f] += r2[f + s2]; }
            __syncthreads();
        }
        if (f == 0) { as_[n] = clampf(r1[0]); ad_[n] = clampf(r2[0]); }
    } else {
        int e = (bid - (NR + NC)) * 128 + threadIdx.x;
        if (e < ER) {
            unsigned d = (unsigned)dstR[e];
            if (d < (unsigned)NR) {
                int p = offR[d] + atomicAdd(&curR[d], 1);
                sortedR[p] = clampi(srcR[e], 0, NR - 1);
            }
        } else if (e < ER + EC) {
            int e2 = e - ER;
            unsigned d = (unsigned)dstC[e2];
            if (d < (unsigned)NC) {
                int p = offC[d] + atomicAdd(&curC[d], 1);
                sortedC[p] = clampi(srcC[e2], 0, NC - 1);
            }
        }
    }
}

// ---------------- fused layer-2 linear (both branches, fp32 input) ----------------
__global__ __launch_bounds__(128) void k_lin2_both(
    const float* __restrict__ xR, const void* __restrict__ WR,
    const void* __restrict__ avsR, const void* __restrict__ avdR,
    float* __restrict__ hR, float* __restrict__ asR, float* __restrict__ adR, int NR,
    const float* __restrict__ xC, const void* __restrict__ WC,
    const void* __restrict__ avsC, const void* __restrict__ avdC,
    float* __restrict__ hC, float* __restrict__ asC, float* __restrict__ adC, int NC,
    const int* __restrict__ mode_p) {
    int mode = *mode_p;
    int bid = blockIdx.x;
    int f = threadIdx.x;
    const float* x;
    const void *W, *avs, *avd;
    float *h, *as_, *ad_;
    int n;
    if (bid < NR) { n = bid; x = xR; W = WR; avs = avsR; avd = avdR; h = hR; as_ = asR; ad_ = adR; }
    else          { n = bid - NR; x = xC; W = WC; avs = avsC; avd = avdC; h = hC; as_ = asC; ad_ = adC; }
    __shared__ float xs[128];
    __shared__ float r1[128], r2[128];
    xs[f] = x[(size_t)n * 128 + f];
    __syncthreads();
    float acc = 0.f;
#pragma unroll
    for (int k = 0; k < 128; k++) acc += xs[k] * ldm(W, k * 128 + f, mode);
    acc = clampf(acc);
    h[(size_t)n * 128 + f] = acc;
    r1[f] = acc * ldm(avs, f, mode);
    r2[f] = acc * ldm(avd, f, mode);
    __syncthreads();
    for (int s2 = 64; s2 > 0; s2 >>= 1) {
        if (f < s2) { r1[f] += r1[f + s2]; r2[f] += r2[f + s2]; }
        __syncthreads();
    }
    if (f == 0) { as_[n] = clampf(r1[0]); ad_[n] = clampf(r2[0]); }
}

// ---------------- fused softmax-aggregate (both branches; optional rn epilogue) ----------------
__global__ __launch_bounds__(256) void k_agg_both(
    const float* __restrict__ hR, const float* __restrict__ asR, const float* __restrict__ adR,
    const int* __restrict__ offR, const int* __restrict__ srtR, const void* __restrict__ biasR,
    float* __restrict__ outR, int NR,
    const float* __restrict__ hC, const float* __restrict__ asC, const float* __restrict__ adC,
    const int* __restrict__ offC, const int* __restrict__ srtC, const void* __restrict__ biasC,
    float* __restrict__ outC, int NC,
    const int* __restrict__ mode_p, int blocksR, float* __restrict__ rn, int do_rn) {
    int mode = *mode_p;
    int bid = blockIdx.x;
    int wid = threadIdx.x >> 6;
    int lane = threadIdx.x & 63;
    const float *h, *as_, *ad_;
    const int *off, *sorted;
    const void* bias;
    float* out;
    int w, N, isR;
    if (bid < blocksR) { isR = 1; w = bid * 4 + wid; N = NR; h = hR; as_ = asR; ad_ = adR; off = offR; sorted = srtR; bias = biasR; out = outR; }
    else               { isR = 0; w = (bid - blocksR) * 4 + wid; N = NC; h = hC; as_ = asC; ad_ = adC; off = offC; sorted = srtC; bias = biasC; out = outC; }
    if (w >= N) return;
    int s0 = off[w], s1 = off[w + 1];
    float adv = ad_[w];
    float eself = lrelu(as_[w] + adv);
    float m = eself;
    for (int j = s0 + lane; j < s1; j += 64) {
        int s = clampi(sorted[j], 0, N - 1);
        m = fmaxf(m, lrelu(as_[s] + adv));
    }
#pragma unroll
    for (int d = 32; d > 0; d >>= 1) m = fmaxf(m, __shfl_xor(m, d, 64));
    const float2* h2 = (const float2*)h;
    float wself = __expf(eself - m);
    float denom = wself;
    float2 hv = h2[(size_t)w * 64 + lane];
    float a0 = wself * hv.x, a1 = wself * hv.y;
    for (int j = s0; j < s1; j++) {
        int s = clampi(sorted[j], 0, N - 1);
        float wj = __expf(lrelu(as_[s] + adv) - m);
        denom += wj;
        float2 hs = h2[(size_t)s * 64 + lane];
        a0 += wj * hs.x;
        a1 += wj * hs.y;
    }
    float inv = 1.f / fmaxf(denom, 1e-30f);
    float o0 = fminf(fmaxf(a0 * inv + ldm(bias, lane * 2, mode), 0.f), 1e15f);
    float o1 = fminf(fmaxf(a1 * inv + ldm(bias, lane * 2 + 1, mode), 0.f), 1e15f);
    out[(size_t)w * 128 + lane * 2] = o0;
    out[(size_t)w * 128 + lane * 2 + 1] = o1;
    if (do_rn && isR) {
        float s = o0 * o0 + o1 * o1;
#pragma unroll
        for (int d = 32; d > 0; d >>= 1) s += __shfl_xor(s, d, 64);
        if (lane == 0) rn[w] = s;
    }
}

// ---------------- kNN partial: ROUND-13 restructure ----------------
// A-tile (64 colliders, full K=128) staged ONCE in LDS (stride 132, conflict-free
// b128 reads, 33.8 KB); B (resting rows) read DIRECTLY from global as float4 —
// 8 lanes share each address (coalesced 128 B/instr), hr is L2-resident with 79x
// cross-block reuse. Removes 4 of 12 LDS reads per kk4 AND all in-loop barriers:
// LDS pipe 144 -> 96 cyc per 64-cyc-VALU step (ceiling 44% -> 67%).
// Accumulation order per (c,r) unchanged (kk4 asc, x,y,z,w) -> bit-identical.
// unroll 2 retained (anti-spill, rounds 9-12 verified).
// NCH=12: 79x12=948 blocks <= 4 blocks/CU (LDS-limited) x 237 -> one launch wave.
#define KNN_TC 64
#define KNN_TR 128
#define KNN_NCH 12
#define KNN_ASTRIDE 132

__global__ __launch_bounds__(256)
void k_knn_part(const float* __restrict__ hr,
                const float* __restrict__ hc,
                const float* __restrict__ rn,
                float* __restrict__ cand_v, int* __restrict__ cand_i,
                int NR, int NC, int chunk) {
    __shared__ float lds[KNN_TC * KNN_ASTRIDE];  // 8448 floats = 33792 B
    float* hcs = lds;                            // [64][132], full K
    int tid = threadIdx.x;   // 0..255
    int tx = tid & 7;        // 0..7
    int ty = tid >> 3;       // 0..31
    int c0 = blockIdx.x * KNN_TC;
    int rbase = blockIdx.y * chunk;
    int rend = min(rbase + chunk, NR);

    // stage full-K collider tile once: 64 rows x 32 float4 = 2048 items / 256 thr
#pragma unroll
    for (int q = 0; q < 8; q++) {
        int idx = q * 256 + tid;
        int row = idx >> 5, col4 = idx & 31;
        int c = c0 + row;
        float4 v = make_float4(0.f, 0.f, 0.f, 0.f);
        if (c < NC) v = *(const float4*)&hc[(size_t)c * 128 + col4 * 4];
        *(float4*)&hcs[row * KNN_ASTRIDE + col4 * 4] = v;
    }
    __syncthreads();

    float bv[8][3];
    int bi[8][3];
#pragma unroll
    for (int i = 0; i < 8; i++)
#pragma unroll
        for (int j = 0; j < 3; j++) { bv[i][j] = 3.4e38f; bi[i][j] = 0x7fffffff; }

    for (int rt = rbase; rt < rend; rt += KNN_TR) {
        float acc[8][4];
#pragma unroll
        for (int i = 0; i < 8; i++)
#pragma unroll
            for (int j = 0; j < 4; j++) acc[i][j] = 0.f;

        // B row pointers (clamped; invalid rows excluded by scoring guard)
        const float* bp[4];
#pragma unroll
        for (int j = 0; j < 4; j++) {
            int r = min(rt + ty + 32 * j, NR - 1);
            bp[j] = &hr[(size_t)r * 128];
        }

#pragma unroll 2
        for (int kk4 = 0; kk4 < 32; kk4++) {
            float4 b[4];
#pragma unroll
            for (int j = 0; j < 4; j++)
                b[j] = *(const float4*)&bp[j][kk4 * 4];
#pragma unroll
            for (int i = 0; i < 8; i++) {
                float4 a = *(const float4*)&hcs[(tx + 8 * i) * KNN_ASTRIDE + kk4 * 4];
#pragma unroll
                for (int j = 0; j < 4; j++) {
                    acc[i][j] += a.x * b[j].x;
                    acc[i][j] += a.y * b[j].y;
                    acc[i][j] += a.z * b[j].z;
                    acc[i][j] += a.w * b[j].w;
                }
            }
        }
        // score + top3 update (rank by rn[r] - 2*dot)
#pragma unroll
        for (int j = 0; j < 4; j++) {
            int r = rt + ty + 32 * j;
            if (r < rend) {
                float rnv = rn[r];
#pragma unroll
                for (int i = 0; i < 8; i++) {
                    float d = rnv - 2.f * acc[i][j];
                    ins3(d, r, bv[i], bi[i]);
                }
            }
        }
    }

    // two-pass merge across the 32 ty-groups (LDS scratch 24.6 KB <= 33.8 KB)
    float* mv = lds;
    int* mi = (int*)(lds + KNN_TC * 48);
    float fv[3] = {3.4e38f, 3.4e38f, 3.4e38f};
    int fi[3] = {0x7fffffff, 0x7fffffff, 0x7fffffff};

    __syncthreads();
    if (ty < 16) {
#pragma unroll
        for (int i = 0; i < 8; i++) {
            int cc = tx + 8 * i;
#pragma unroll
            for (int j = 0; j < 3; j++) {
                mv[cc * 48 + ty * 3 + j] = bv[i][j];
                mi[cc * 48 + ty * 3 + j] = bi[i][j];
            }
        }
    }
    __syncthreads();
    if (tid < KNN_TC) {
        for (int t = 0; t < 48; t++) ins3(mv[tid * 48 + t], mi[tid * 48 + t], fv, fi);
    }
    __syncthreads();
    if (ty >= 16) {
#pragma unroll
        for (int i = 0; i < 8; i++) {
            int cc = tx + 8 * i;
#pragma unroll
            for (int j = 0; j < 3; j++) {
                mv[cc * 48 + (ty - 16) * 3 + j] = bv[i][j];
                mi[cc * 48 + (ty - 16) * 3 + j] = bi[i][j];
            }
        }
    }
    __syncthreads();
    if (tid < KNN_TC) {
        for (int t = 0; t < 48; t++) ins3(mv[tid * 48 + t], mi[tid * 48 + t], fv, fi);
        int c = c0 + tid;
        if (c < NC) {
            size_t o = ((size_t)c * KNN_NCH + blockIdx.y) * 3;
            cand_v[o + 0] = fv[0]; cand_i[o + 0] = fi[0];
            cand_v[o + 1] = fv[1]; cand_i[o + 1] = fi[1];
            cand_v[o + 2] = fv[2]; cand_i[o + 2] = fi[2];
        }
    }
}

// ---------------- fused kNN merge + pooling scatter (one block per collider) ----------------
__global__ __launch_bounds__(128) void k_mergepool(const float* __restrict__ cand_v,
                                                   const int* __restrict__ cand_i,
                                                   const float* __restrict__ hc,
                                                   float* __restrict__ psum, float* __restrict__ pcnt,
                                                   int NC, int NR) {
    int c = blockIdx.x;
    int f = threadIdx.x;
    __shared__ int kn[3];
    if (f == 0) {
        float fv[3] = {3.4e38f, 3.4e38f, 3.4e38f};
        int fi[3] = {0x7fffffff, 0x7fffffff, 0x7fffffff};
        size_t o = (size_t)c * KNN_NCH * 3;
        for (int t = 0; t < KNN_NCH * 3; t++) ins3(cand_v[o + t], cand_i[o + t], fv, fi);
#pragma unroll
        for (int j = 0; j < 3; j++) {
            kn[j] = clampi(fi[j], 0, NR - 1);
            atomicAdd(&pcnt[kn[j]], 1.f);
        }
    }
    __syncthreads();
    float v = hc[(size_t)c * 128 + f];
#pragma unroll
    for (int j = 0; j < 3; j++) atomicAdd(&psum[(size_t)kn[j] * 128 + f], v);
}

// ---------------- decode: out = [hr, pooled] @ Wd + bd ----------------
__global__ __launch_bounds__(256) void k_decode(const float* __restrict__ hr, const float* __restrict__ psum,
                                                const float* __restrict__ pcnt,
                                                const void* __restrict__ Wd,
                                                const void* __restrict__ bd,
                                                const int* __restrict__ mode_p,
                                                void* __restrict__ outv, int NR) {
    int mode = *mode_p;
    int w = (blockIdx.x * blockDim.x + threadIdx.x) >> 6;
    int lane = threadIdx.x & 63;
    if (w >= NR) return;
    float icnt = 1.f / fmaxf(pcnt[w], 1.f);
    float o0 = 0.f, o1 = 0.f, o2 = 0.f;
#pragma unroll
    for (int hh = 0; hh < 2; hh++) {
        int f = lane + hh * 64;
        float xv = hr[(size_t)w * 128 + f];
        o0 += xv * ldm(Wd, f * 3 + 0, mode);
        o1 += xv * ldm(Wd, f * 3 + 1, mode);
        o2 += xv * ldm(Wd, f * 3 + 2, mode);
        float pv = psum[(size_t)w * 128 + f] * icnt;
        o0 += pv * ldm(Wd, (128 + f) * 3 + 0, mode);
        o1 += pv * ldm(Wd, (128 + f) * 3 + 1, mode);
        o2 += pv * ldm(Wd, (128 + f) * 3 + 2, mode);
    }
#pragma unroll
    for (int d = 32; d > 0; d >>= 1) {
        o0 += __shfl_xor(o0, d, 64);
        o1 += __shfl_xor(o1, d, 64);
        o2 += __shfl_xor(o2, d, 64);
    }
    if (lane == 0) {
        float v0 = o0 + ldm(bd, 0, mode);
        float v1 = o1 + ldm(bd, 1, mode);
        float v2 = o2 + ldm(bd, 2, mode);
        if (mode) {
            float* out = (float*)outv;
            out[w * 3 + 0] = v0;
            out[w * 3 + 1] = v1;
            out[w * 3 + 2] = v2;
        } else {
            __hip_bfloat16* out = (__hip_bfloat16*)outv;
            out[w * 3 + 0] = __float2bfloat16(v0);
            out[w * 3 + 1] = __float2bfloat16(v1);
            out[w * 3 + 2] = __float2bfloat16(v2);
        }
    }
}

extern "C" void kernel_launch(void* const* d_in, const int* in_sizes, int n_in,
                              void* d_out, int out_size, void* d_ws, size_t ws_size,
                              hipStream_t stream) {
    const void* x_r = d_in[0];
    const int* ei_r = (const int*)d_in[1];
    const void* x_c = d_in[2];
    const int* ei_c = (const int*)d_in[3];
    const void* W1r = d_in[4];
    const void* as1r = d_in[5];
    const void* ad1r = d_in[6];
    const void* b1r = d_in[7];
    const void* W2r = d_in[8];
    const void* as2r = d_in[9];
    const void* ad2r = d_in[10];
    const void* b2r = d_in[11];
    const void* W1c = d_in[12];
    const void* as1c = d_in[13];
    const void* ad1c = d_in[14];
    const void* b1c = d_in[15];
    const void* W2c = d_in[16];
    const void* as2c = d_in[17];
    const void* ad2c = d_in[18];
    const void* b2c = d_in[19];
    const void* Wd = d_in[20];
    const void* bd = d_in[21];

    const int NR = in_sizes[0] / 3;
    const int ER = in_sizes[1] / 2;
    const int NC = in_sizes[2] / 6;
    const int EC = in_sizes[3] / 2;

    // ---- workspace layout: non-zeroed region first, then ONE contiguous zero region ----
    char* p = (char*)d_ws;
    size_t used = 0;
    auto alloc = [&](size_t bytes) {
        void* q = (void*)(p + used);
        used += (bytes + 255) & ~(size_t)255;
        return q;
    };
    float* r_A = (float*)alloc((size_t)NR * 128 * 4);
    float* r_B = (float*)alloc((size_t)NR * 128 * 4);
    float* c_A = (float*)alloc((size_t)NC * 128 * 4);  // later cand_v/cand_i alias
    float* c_B = (float*)alloc((size_t)NC * 128 * 4);
    float* r_as = (float*)alloc((size_t)NR * 4);
    float* r_ad = (float*)alloc((size_t)NR * 4);
    float* c_as = (float*)alloc((size_t)NC * 4);
    float* c_ad = (float*)alloc((size_t)NC * 4);
    float* rn = (float*)alloc((size_t)NR * 4);
    int* r_off = (int*)alloc((size_t)(NR + 1) * 4);
    int* r_sorted = (int*)alloc((size_t)ER * 4);
    int* c_off = (int*)alloc((size_t)(NC + 1) * 4);
    int* c_sorted = (int*)alloc((size_t)EC * 4);
    // zero region (single memset covers all of these, padding included)
    size_t zero_off = used;
    float* psum = (float*)alloc((size_t)NR * 128 * 4);
    float* pcnt = (float*)alloc((size_t)NR * 4);
    int* r_deg = (int*)alloc((size_t)NR * 4);
    int* r_cur = (int*)alloc((size_t)NR * 4);
    int* c_deg = (int*)alloc((size_t)NC * 4);
    int* c_cur = (int*)alloc((size_t)NC * 4);
    int* mode_p = (int*)alloc(256);
    size_t zero_len = used - zero_off;

    // aliases (c_A dead after collider agg2)
    float* cand_v = c_A;
    int* cand_i = (int*)(c_A + (size_t)NC * KNN_NCH * 3);

    if (ws_size < used) return;  // tripwire

    (void)hipMemsetAsync(p + zero_off, 0, zero_len, stream);

    // ---- fused hist (both graphs) + dtype detect ----
    int histBlocks = (ER + EC + 255) / 256;
    int detBlocks = (in_sizes[0] + in_sizes[2] + 255) / 256;
    k_pre<<<histBlocks + detBlocks, 256, 0, stream>>>(
        ei_r + ER, ER, r_deg, NR, ei_c + EC, EC, c_deg, NC,
        (const unsigned short*)x_r, in_sizes[0], (const unsigned short*)x_c, in_sizes[2],
        mode_p, histBlocks);

    // ---- low-barrier scan (both graphs, 2 blocks) ----
    k_scan2<<<2, 1024, 0, stream>>>(r_deg, r_off, NR, c_deg, c_off, NC);

    // ---- fused scatter (both graphs) + layer-1 linear (both branches) ----
    int scatBlocks = (ER + EC + 127) / 128;
    k_scatlin<<<NR + NC + scatBlocks, 128, 0, stream>>>(
        x_r, W1r, as1r, ad1r, r_A, r_as, r_ad, NR,
        x_c, W1c, as1c, ad1c, c_A, c_as, c_ad, NC, mode_p,
        ei_r, ei_r + ER, ER, r_off, r_cur, r_sorted,
        ei_c, ei_c + EC, EC, c_off, c_cur, c_sorted);

    const int aggBlocksR = (NR * 64 + 255) / 256;
    const int aggBlocksC = (NC * 64 + 255) / 256;

    // ---- GAT layer 1 aggregate (both branches) ----
    k_agg_both<<<aggBlocksR + aggBlocksC, 256, 0, stream>>>(
        r_A, r_as, r_ad, r_off, r_sorted, b1r, r_B, NR,
        c_A, c_as, c_ad, c_off, c_sorted, b1c, c_B, NC, mode_p, aggBlocksR, rn, 0);

    // ---- GAT layer 2 (both branches): lin(B) -> A, agg -> B; resting agg also writes rn ----
    k_lin2_both<<<NR + NC, 128, 0, stream>>>(r_B, W2r, as2r, ad2r, r_A, r_as, r_ad, NR,
                                             c_B, W2c, as2c, ad2c, c_A, c_as, c_ad, NC, mode_p);
    k_agg_both<<<aggBlocksR + aggBlocksC, 256, 0, stream>>>(
        r_A, r_as, r_ad, r_off, r_sorted, b2r, r_B, NR,
        c_A, c_as, c_ad, c_off, c_sorted, b2c, c_B, NC, mode_p, aggBlocksR, rn, 1);

    // ---- kNN + fused merge/pool ----
    int chunk = (NR + KNN_NCH - 1) / KNN_NCH;
    dim3 kg((NC + KNN_TC - 1) / KNN_TC, KNN_NCH);
    k_knn_part<<<kg, 256, 0, stream>>>(r_B, c_B, rn, cand_v, cand_i, NR, NC, chunk);
    k_mergepool<<<NC, 128, 0, stream>>>(cand_v, cand_i, c_B, psum, pcnt, NC, NR);

    // ---- decode ----
    k_decode<<<aggBlocksR, 256, 0, stream>>>(r_B, psum, pcnt, Wd, bd, mode_p, d_out, NR);
}